// Round 1
// baseline (68829.034 us; speedup 1.0000x reference)
//
#include <hip/hip_runtime.h>
#include <hip/hip_bf16.h>

#define T_   64
#define N_   50000
#define E_   1600000
#define GH_  32
#define RH_  64

static __device__ __forceinline__ float fast_sigmoid(float v) {
    float e = __expf(-v);
    return __builtin_amdgcn_rcpf(1.0f + e);
}
static __device__ __forceinline__ float fast_tanh(float v) {
    return 2.0f * fast_sigmoid(2.0f * v) - 1.0f;
}

// ---------- prologue ----------
__global__ void k_deg(const int* __restrict__ dst, float* __restrict__ deg) {
    int e = blockIdx.x * blockDim.x + threadIdx.x;
    if (e < E_) atomicAdd(&deg[dst[e]], 1.0f);
}

__global__ void k_node_init(const float* __restrict__ deg,
                            const float* __restrict__ statics,   // [N,6]
                            const float* __restrict__ w0,        // [7,32]
                            const float* __restrict__ dyn0,      // dyn_seq t=0
                            float* __restrict__ dinv,
                            float* __restrict__ selfn,
                            float* __restrict__ h0s,             // [N,32]
                            float* __restrict__ csagg,           // [N,32]
                            float* __restrict__ a) {             // [N]
    int n = blockIdx.x * blockDim.x + threadIdx.x;
    if (n >= N_) return;
    float d  = deg[n] + 1.0f;           // + self loop
    float di = rsqrtf(d);
    dinv[n] = di;
    float sn = di * di;
    selfn[n] = sn;
    float s[6];
#pragma unroll
    for (int j = 0; j < 6; ++j) s[j] = statics[n * 6 + j];
#pragma unroll
    for (int k = 0; k < GH_; ++k) {
        float v = 0.0f;
#pragma unroll
        for (int j = 0; j < 6; ++j) v += s[j] * w0[(1 + j) * GH_ + k];
        h0s[n * GH_ + k]   = v;
        csagg[n * GH_ + k] = sn * v;    // self-loop term
    }
    a[n] = sn * dyn0[n];                // self-loop term of a_0
}

// 8 threads per edge, float4 each; also stores normE
__global__ void k_edge_cs(const int* __restrict__ src, const int* __restrict__ dst,
                          const float* __restrict__ dinv, const float* __restrict__ h0s,
                          float* __restrict__ normE, float* __restrict__ csagg) {
    unsigned gid = blockIdx.x * blockDim.x + threadIdx.x;
    unsigned e = gid >> 3, sub = gid & 7;
    if (e >= E_) return;
    int s = src[e], d = dst[e];
    float nm = dinv[s] * dinv[d];
    if (sub == 0) normE[e] = nm;
    float4 v = ((const float4*)(h0s + s * GH_))[sub];
    float* out = csagg + d * GH_ + sub * 4;
    atomicAdd(out + 0, nm * v.x);
    atomicAdd(out + 1, nm * v.y);
    atomicAdd(out + 2, nm * v.z);
    atomicAdd(out + 3, nm * v.w);
}

// ---------- per-timestep ----------
__global__ void k_edge_a(const int* __restrict__ src, const int* __restrict__ dst,
                         const float* __restrict__ normE,
                         const float* __restrict__ dyn_t, float* __restrict__ a) {
    int e = blockIdx.x * blockDim.x + threadIdx.x;
    if (e < E_) atomicAdd(&a[dst[e]], normE[e] * dyn_t[src[e]]);
}

__global__ __launch_bounds__(256)
void k_transform(const float* __restrict__ a, const float* __restrict__ csagg,
                 const float* __restrict__ w0,      // row 0 used
                 const float* __restrict__ b0,
                 const float* __restrict__ w1,      // [32,32]
                 const float* __restrict__ selfn,
                 float* __restrict__ g1, float* __restrict__ agg2) {
    int n = blockIdx.x * blockDim.x + threadIdx.x;
    if (n >= N_) return;
    float av = a[n];
    float h1[GH_];
#pragma unroll
    for (int k = 0; k < GH_; ++k) {
        float v = av * w0[k] + csagg[n * GH_ + k] + b0[k];
        h1[k] = v > 0.0f ? v : 0.0f;
    }
    float sn = selfn[n];
#pragma unroll
    for (int j = 0; j < GH_; ++j) {
        float v = 0.0f;
#pragma unroll
        for (int k = 0; k < GH_; ++k) v += h1[k] * w1[k * GH_ + j];
        g1[n * GH_ + j]   = v;
        agg2[n * GH_ + j] = sn * v;     // self-loop init
    }
}

__global__ void k_edge_g(const int* __restrict__ src, const int* __restrict__ dst,
                         const float* __restrict__ normE,
                         const float* __restrict__ g1, float* __restrict__ agg2) {
    unsigned gid = blockIdx.x * blockDim.x + threadIdx.x;
    unsigned e = gid >> 3, sub = gid & 7;
    if (e >= E_) return;
    int s = src[e], d = dst[e];
    float nm = normE[e];
    float4 v = ((const float4*)(g1 + s * GH_))[sub];
    float* out = agg2 + d * GH_ + sub * 4;
    atomicAdd(out + 0, nm * v.x);
    atomicAdd(out + 1, nm * v.y);
    atomicAdd(out + 2, nm * v.z);
    atomicAdd(out + 3, nm * v.w);
}

__global__ __launch_bounds__(256)
void k_gru(const float* __restrict__ agg2, const float* __restrict__ b1,
           const float* __restrict__ wih,   // [192,32]
           const float* __restrict__ whh,   // [192,64]
           const float* __restrict__ bih, const float* __restrict__ bhh,
           float* __restrict__ hT,          // [64,N] transposed state
           const float* __restrict__ dyn_next,
           const float* __restrict__ selfn, float* __restrict__ a,
           int have_next) {
    int n = blockIdx.x * blockDim.x + threadIdx.x;
    if (n >= N_) return;
    float x[GH_];
#pragma unroll
    for (int k = 0; k < GH_; ++k) {
        float v = agg2[n * GH_ + k] + b1[k];
        x[k] = v > 0.0f ? v : 0.0f;     // H_t = relu(agg2 + b1)
    }
    float h[RH_];
#pragma unroll
    for (int k = 0; k < RH_; ++k) h[k] = hT[k * N_ + n];
#pragma unroll 1
    for (int j = 0; j < RH_; ++j) {
        float xr = bih[j], xz = bih[RH_ + j], xn = bih[2 * RH_ + j];
#pragma unroll
        for (int k = 0; k < GH_; ++k) {
            float xv = x[k];
            xr += wih[j * GH_ + k] * xv;
            xz += wih[(RH_ + j) * GH_ + k] * xv;
            xn += wih[(2 * RH_ + j) * GH_ + k] * xv;
        }
        float hr = bhh[j], hz = bhh[RH_ + j], hn = bhh[2 * RH_ + j];
#pragma unroll
        for (int k = 0; k < RH_; ++k) {
            float hv = h[k];
            hr += whh[j * RH_ + k] * hv;
            hz += whh[(RH_ + j) * RH_ + k] * hv;
            hn += whh[(2 * RH_ + j) * RH_ + k] * hv;
        }
        float r = fast_sigmoid(xr + hr);
        float z = fast_sigmoid(xz + hz);
        float c = fast_tanh(xn + r * hn);
        hT[j * N_ + n] = (1.0f - z) * c + z * h[j];
    }
    if (have_next) a[n] = selfn[n] * dyn_next[n];  // init a_{t+1} (incl. self loop)
}

__global__ __launch_bounds__(256)
void k_mlp(const float* __restrict__ hT, const float* __restrict__ w1,
           const float* __restrict__ b1, const float* __restrict__ w2,
           const float* __restrict__ b2, float* __restrict__ out) {
    int n = blockIdx.x * blockDim.x + threadIdx.x;
    if (n >= N_) return;
    float h[RH_];
#pragma unroll
    for (int k = 0; k < RH_; ++k) h[k] = hT[k * N_ + n];
    float acc = b2[0];
#pragma unroll 1
    for (int j = 0; j < RH_; ++j) {
        float v = b1[j];
#pragma unroll
        for (int k = 0; k < RH_; ++k) v += w1[j * RH_ + k] * h[k];
        v = v > 0.0f ? v : 0.0f;
        acc += w2[j] * v;
    }
    out[n] = acc;
}

extern "C" void kernel_launch(void* const* d_in, const int* in_sizes, int n_in,
                              void* d_out, int out_size, void* d_ws, size_t ws_size,
                              hipStream_t stream) {
    const float* dyn     = (const float*)d_in[0];
    const float* statics = (const float*)d_in[1];
    const int*   ei      = (const int*)d_in[2];
    const float* w0      = (const float*)d_in[3];
    const float* b0      = (const float*)d_in[4];
    const float* w1      = (const float*)d_in[5];
    const float* b1      = (const float*)d_in[6];
    const float* wih     = (const float*)d_in[7];
    const float* whh     = (const float*)d_in[8];
    const float* bih     = (const float*)d_in[9];
    const float* bhh     = (const float*)d_in[10];
    const float* mw1     = (const float*)d_in[11];
    const float* mb1     = (const float*)d_in[12];
    const float* mw2     = (const float*)d_in[13];
    const float* mb2     = (const float*)d_in[14];
    const int* src = ei;
    const int* dst = ei + E_;

    float* ws    = (float*)d_ws;
    float* deg   = ws;                  // N
    float* dinv  = deg   + N_;          // N
    float* selfn = dinv  + N_;          // N
    float* a     = selfn + N_;          // N
    float* normE = a     + N_;          // E
    float* h0s   = normE + E_;          // 32N
    float* csagg = h0s   + 32 * N_;     // 32N
    float* g1    = csagg + 32 * N_;     // 32N
    float* agg2  = g1    + 32 * N_;     // 32N
    float* hT    = agg2  + 32 * N_;     // 64N

    auto cdiv = [](long long x, int b) { return (unsigned)((x + b - 1) / b); };
    const int B = 256;

    hipMemsetAsync(deg, 0, N_ * sizeof(float), stream);
    hipMemsetAsync(hT, 0, (size_t)RH_ * N_ * sizeof(float), stream);

    k_deg<<<cdiv(E_, B), B, 0, stream>>>(dst, deg);
    k_node_init<<<cdiv(N_, B), B, 0, stream>>>(deg, statics, w0, dyn,
                                               dinv, selfn, h0s, csagg, a);
    k_edge_cs<<<cdiv((long long)E_ * 8, B), B, 0, stream>>>(src, dst, dinv, h0s,
                                                            normE, csagg);
    for (int t = 0; t < T_; ++t) {
        k_edge_a<<<cdiv(E_, B), B, 0, stream>>>(src, dst, normE,
                                                dyn + (long long)t * N_, a);
        k_transform<<<cdiv(N_, B), B, 0, stream>>>(a, csagg, w0, b0, w1, selfn,
                                                   g1, agg2);
        k_edge_g<<<cdiv((long long)E_ * 8, B), B, 0, stream>>>(src, dst, normE,
                                                               g1, agg2);
        k_gru<<<cdiv(N_, B), B, 0, stream>>>(agg2, b1, wih, whh, bih, bhh, hT,
                                             dyn + (long long)(t + 1) * N_,
                                             selfn, a, (t + 1 < T_) ? 1 : 0);
    }
    k_mlp<<<cdiv(N_, B), B, 0, stream>>>(hT, mw1, mb1, mw2, mb2, (float*)d_out);
}

// Round 2
// 21676.413 us; speedup vs baseline: 3.1753x; 3.1753x over previous
//
#include <hip/hip_runtime.h>
#include <hip/hip_bf16.h>

#define T_   64
#define N_   50000
#define E_   1600000
#define GH_  32
#define RH_  64

static __device__ __forceinline__ float fast_sigmoid(float v) {
    float e = __expf(-v);
    return __builtin_amdgcn_rcpf(1.0f + e);
}
static __device__ __forceinline__ float fast_tanh(float v) {
    return 2.0f * fast_sigmoid(2.0f * v) - 1.0f;
}

// ---------- prologue ----------

// dyn [T,N] -> dynT [N,T]   (LDS-tiled transpose)
__global__ __launch_bounds__(256)
void k_transpose(const float* __restrict__ dyn, float* __restrict__ dynT) {
    __shared__ float tile[64][65];
    int n0 = blockIdx.x * 64;
    int tx = threadIdx.x;          // 0..63
    int ty = threadIdx.y;          // 0..3
#pragma unroll
    for (int r = 0; r < 16; ++r) {
        int t = r * 4 + ty;
        int n = n0 + tx;
        tile[t][tx] = (n < N_) ? dyn[(size_t)t * N_ + n] : 0.0f;
    }
    __syncthreads();
#pragma unroll
    for (int r = 0; r < 16; ++r) {
        int nl = r * 4 + ty;
        int n = n0 + nl;
        if (n < N_) dynT[(size_t)n * 64 + tx] = tile[tx][nl];
    }
}

__global__ void k_deg(const int* __restrict__ dst, int* __restrict__ deg) {
    int e = blockIdx.x * blockDim.x + threadIdx.x;
    if (e < E_) atomicAdd(&deg[dst[e]], 1);
}

// single-block inclusive scan -> row_ptr (exclusive, row_ptr[0]=0)
__global__ __launch_bounds__(1024)
void k_scan(const int* __restrict__ deg, int* __restrict__ row_ptr) {
    __shared__ int buf[1024];
    __shared__ int carry;
    int tid = threadIdx.x;
    if (tid == 0) { carry = 0; row_ptr[0] = 0; }
    __syncthreads();
    for (int base = 0; base < N_; base += 1024) {
        int i = base + tid;
        int v = (i < N_) ? deg[i] : 0;
        buf[tid] = v;
        __syncthreads();
        for (int off = 1; off < 1024; off <<= 1) {
            int t = (tid >= off) ? buf[tid - off] : 0;
            __syncthreads();
            buf[tid] += t;
            __syncthreads();
        }
        if (i < N_) row_ptr[i + 1] = carry + buf[tid];
        __syncthreads();
        if (tid == 0) carry += buf[1023];
        __syncthreads();
    }
}

__global__ __launch_bounds__(256)
void k_node_init(const int* __restrict__ deg,
                 const float* __restrict__ statics,   // [N,6]
                 const float* __restrict__ w0,        // [7,32]
                 float* __restrict__ dinv,
                 float* __restrict__ selfn,
                 float* __restrict__ h0s) {           // [N,32]
    int n = blockIdx.x * blockDim.x + threadIdx.x;
    if (n >= N_) return;
    float d  = (float)deg[n] + 1.0f;     // + self loop
    float di = rsqrtf(d);
    dinv[n] = di;
    selfn[n] = di * di;
    float s[6];
#pragma unroll
    for (int j = 0; j < 6; ++j) s[j] = statics[n * 6 + j];
#pragma unroll
    for (int k = 0; k < GH_; ++k) {
        float v = 0.0f;
#pragma unroll
        for (int j = 0; j < 6; ++j) v += s[j] * w0[(1 + j) * GH_ + k];
        h0s[n * GH_ + k] = v;
    }
}

__global__ void k_scatter(const int* __restrict__ src, const int* __restrict__ dst,
                          const float* __restrict__ dinv,
                          const int* __restrict__ row_ptr, int* __restrict__ cursor,
                          int* __restrict__ csr_src, float* __restrict__ csr_nm) {
    int e = blockIdx.x * blockDim.x + threadIdx.x;
    if (e >= E_) return;
    int s = src[e], d = dst[e];
    int pos = row_ptr[d] + atomicAdd(&cursor[d], 1);
    csr_src[pos] = s;
    csr_nm[pos]  = dinv[s] * dinv[d];
}

// aT[n][t] = selfn[n]*dynT[n][t] + sum_e nm*dynT[src][t]   (wave per node, lane=t)
__global__ __launch_bounds__(256)
void k_aall(const int* __restrict__ row_ptr, const int* __restrict__ csr_src,
            const float* __restrict__ csr_nm, const float* __restrict__ selfn,
            const float* __restrict__ dynT, float* __restrict__ aT) {
    int gid = blockIdx.x * 256 + threadIdx.x;
    int n = gid >> 6, lane = gid & 63;
    if (n >= N_) return;
    float acc = selfn[n] * dynT[(size_t)n * 64 + lane];
    int e0 = row_ptr[n], e1 = row_ptr[n + 1];
    for (int e = e0; e < e1; ++e) {
        acc += csr_nm[e] * dynT[(size_t)csr_src[e] * 64 + lane];
    }
    aT[(size_t)n * 64 + lane] = acc;
}

// out[n][:] = selfn[n]*feat[n][:] + sum_e nm*feat[src][:]  (8 lanes/node, float4)
__global__ __launch_bounds__(256)
void k_gather32(const int* __restrict__ row_ptr, const int* __restrict__ csr_src,
                const float* __restrict__ csr_nm, const float* __restrict__ selfn,
                const float* __restrict__ feat, float* __restrict__ out) {
    int gid = blockIdx.x * 256 + threadIdx.x;
    int n = gid >> 3, q = gid & 7;
    if (n >= N_) return;
    const float4* f4 = (const float4*)feat;
    float4 acc = f4[n * 8 + q];
    float sn = selfn[n];
    acc.x *= sn; acc.y *= sn; acc.z *= sn; acc.w *= sn;
    int e0 = row_ptr[n], e1 = row_ptr[n + 1];
    for (int e = e0; e < e1; ++e) {
        int s = csr_src[e];
        float nm = csr_nm[e];
        float4 v = f4[s * 8 + q];
        acc.x += nm * v.x; acc.y += nm * v.y; acc.z += nm * v.z; acc.w += nm * v.w;
    }
    ((float4*)out)[n * 8 + q] = acc;
}

// ---------- per-timestep ----------
__global__ __launch_bounds__(256)
void k_transform(const float* __restrict__ aT, int t,
                 const float* __restrict__ csagg,
                 const float* __restrict__ w0,      // row 0 used
                 const float* __restrict__ b0,
                 const float* __restrict__ w1,      // [32,32]
                 float* __restrict__ g1) {
    int n = blockIdx.x * blockDim.x + threadIdx.x;
    if (n >= N_) return;
    float av = aT[(size_t)n * 64 + t];
    float h1[GH_];
#pragma unroll
    for (int k = 0; k < GH_; ++k) {
        float v = av * w0[k] + csagg[n * GH_ + k] + b0[k];
        h1[k] = v > 0.0f ? v : 0.0f;
    }
#pragma unroll
    for (int j = 0; j < GH_; ++j) {
        float v = 0.0f;
#pragma unroll
        for (int k = 0; k < GH_; ++k) v += h1[k] * w1[k * GH_ + j];
        g1[n * GH_ + j] = v;
    }
}

__global__ __launch_bounds__(256)
void k_gru(const float* __restrict__ agg2, const float* __restrict__ b1,
           const float* __restrict__ wih,   // [192,32]
           const float* __restrict__ whh,   // [192,64]
           const float* __restrict__ bih, const float* __restrict__ bhh,
           float* __restrict__ hT) {        // [64,N] transposed state
    int n = blockIdx.x * blockDim.x + threadIdx.x;
    if (n >= N_) return;
    float x[GH_];
#pragma unroll
    for (int k = 0; k < GH_; ++k) {
        float v = agg2[n * GH_ + k] + b1[k];
        x[k] = v > 0.0f ? v : 0.0f;     // H_t = relu(agg2 + b1)
    }
    float h[RH_];
#pragma unroll
    for (int k = 0; k < RH_; ++k) h[k] = hT[(size_t)k * N_ + n];
#pragma unroll 1
    for (int j = 0; j < RH_; ++j) {
        float xr = bih[j], xz = bih[RH_ + j], xn = bih[2 * RH_ + j];
#pragma unroll
        for (int k = 0; k < GH_; ++k) {
            float xv = x[k];
            xr += wih[j * GH_ + k] * xv;
            xz += wih[(RH_ + j) * GH_ + k] * xv;
            xn += wih[(2 * RH_ + j) * GH_ + k] * xv;
        }
        float hr = bhh[j], hz = bhh[RH_ + j], hn = bhh[2 * RH_ + j];
#pragma unroll
        for (int k = 0; k < RH_; ++k) {
            float hv = h[k];
            hr += whh[j * RH_ + k] * hv;
            hz += whh[(RH_ + j) * RH_ + k] * hv;
            hn += whh[(2 * RH_ + j) * RH_ + k] * hv;
        }
        float r = fast_sigmoid(xr + hr);
        float z = fast_sigmoid(xz + hz);
        float c = fast_tanh(xn + r * hn);
        hT[(size_t)j * N_ + n] = (1.0f - z) * c + z * h[j];
    }
}

__global__ __launch_bounds__(256)
void k_mlp(const float* __restrict__ hT, const float* __restrict__ w1,
           const float* __restrict__ b1, const float* __restrict__ w2,
           const float* __restrict__ b2, float* __restrict__ out) {
    int n = blockIdx.x * blockDim.x + threadIdx.x;
    if (n >= N_) return;
    float h[RH_];
#pragma unroll
    for (int k = 0; k < RH_; ++k) h[k] = hT[(size_t)k * N_ + n];
    float acc = b2[0];
#pragma unroll 1
    for (int j = 0; j < RH_; ++j) {
        float v = b1[j];
#pragma unroll
        for (int k = 0; k < RH_; ++k) v += w1[j * RH_ + k] * h[k];
        v = v > 0.0f ? v : 0.0f;
        acc += w2[j] * v;
    }
    out[n] = acc;
}

extern "C" void kernel_launch(void* const* d_in, const int* in_sizes, int n_in,
                              void* d_out, int out_size, void* d_ws, size_t ws_size,
                              hipStream_t stream) {
    const float* dyn     = (const float*)d_in[0];
    const float* statics = (const float*)d_in[1];
    const int*   ei      = (const int*)d_in[2];
    const float* w0      = (const float*)d_in[3];
    const float* b0      = (const float*)d_in[4];
    const float* w1      = (const float*)d_in[5];
    const float* b1      = (const float*)d_in[6];
    const float* wih     = (const float*)d_in[7];
    const float* whh     = (const float*)d_in[8];
    const float* bih     = (const float*)d_in[9];
    const float* bhh     = (const float*)d_in[10];
    const float* mw1     = (const float*)d_in[11];
    const float* mb1     = (const float*)d_in[12];
    const float* mw2     = (const float*)d_in[13];
    const float* mb2     = (const float*)d_in[14];
    const int* src = ei;
    const int* dst = ei + E_;

    char* ws = (char*)d_ws;
    auto alloc = [&](size_t elems) { void* p = ws; ws += elems * 4; return p; };
    int*   deg     = (int*)alloc(N_);
    int*   row_ptr = (int*)alloc(N_ + 4);
    int*   cursor  = (int*)alloc(N_);
    int*   csr_src = (int*)alloc(E_);
    float* csr_nm  = (float*)alloc(E_);
    float* dinv    = (float*)alloc(N_);
    float* selfn   = (float*)alloc(N_);
    float* h0s     = (float*)alloc(32 * N_);
    float* csagg   = (float*)alloc(32 * N_);
    float* g1      = (float*)alloc(32 * N_);
    float* agg2    = (float*)alloc(32 * N_);
    float* hT      = (float*)alloc(64 * N_);
    float* dynT    = (float*)alloc(64 * N_);
    float* aT      = (float*)alloc(64 * N_);

    auto cdiv = [](long long x, int b) { return (unsigned)((x + b - 1) / b); };
    const int B = 256;

    hipMemsetAsync(deg, 0, N_ * sizeof(int), stream);
    hipMemsetAsync(cursor, 0, N_ * sizeof(int), stream);
    hipMemsetAsync(hT, 0, (size_t)RH_ * N_ * sizeof(float), stream);

    k_transpose<<<cdiv(N_, 64), dim3(64, 4), 0, stream>>>(dyn, dynT);
    k_deg<<<cdiv(E_, B), B, 0, stream>>>(dst, deg);
    k_scan<<<1, 1024, 0, stream>>>(deg, row_ptr);
    k_node_init<<<cdiv(N_, B), B, 0, stream>>>(deg, statics, w0, dinv, selfn, h0s);
    k_scatter<<<cdiv(E_, B), B, 0, stream>>>(src, dst, dinv, row_ptr, cursor,
                                             csr_src, csr_nm);
    k_gather32<<<cdiv((long long)N_ * 8, B), B, 0, stream>>>(row_ptr, csr_src, csr_nm,
                                                             selfn, h0s, csagg);
    k_aall<<<cdiv((long long)N_ * 64, B), B, 0, stream>>>(row_ptr, csr_src, csr_nm,
                                                          selfn, dynT, aT);

    for (int t = 0; t < T_; ++t) {
        k_transform<<<cdiv(N_, B), B, 0, stream>>>(aT, t, csagg, w0, b0, w1, g1);
        k_gather32<<<cdiv((long long)N_ * 8, B), B, 0, stream>>>(row_ptr, csr_src,
                                                                 csr_nm, selfn, g1, agg2);
        k_gru<<<cdiv(N_, B), B, 0, stream>>>(agg2, b1, wih, whh, bih, bhh, hT);
    }
    k_mlp<<<cdiv(N_, B), B, 0, stream>>>(hT, mw1, mb1, mw2, mb2, (float*)d_out);
}

// Round 3
// 7896.922 us; speedup vs baseline: 8.7159x; 2.7449x over previous
//
#include <hip/hip_runtime.h>
#include <hip/hip_bf16.h>

#define T_   64
#define N_   50000
#define E_   1600000
#define GH_  32
#define RH_  64

static __device__ __forceinline__ float fast_sigmoid(float v) {
    float e = __expf(-v);
    return __builtin_amdgcn_rcpf(1.0f + e);
}
static __device__ __forceinline__ float fast_tanh(float v) {
    return 2.0f * fast_sigmoid(2.0f * v) - 1.0f;
}

// ---------- prologue ----------

// dyn [T,N] -> dynT [N,T]   (LDS-tiled transpose)
__global__ __launch_bounds__(256)
void k_transpose(const float* __restrict__ dyn, float* __restrict__ dynT) {
    __shared__ float tile[64][65];
    int n0 = blockIdx.x * 64;
    int tx = threadIdx.x;          // 0..63
    int ty = threadIdx.y;          // 0..3
#pragma unroll
    for (int r = 0; r < 16; ++r) {
        int t = r * 4 + ty;
        int n = n0 + tx;
        tile[t][tx] = (n < N_) ? dyn[(size_t)t * N_ + n] : 0.0f;
    }
    __syncthreads();
#pragma unroll
    for (int r = 0; r < 16; ++r) {
        int nl = r * 4 + ty;
        int n = n0 + nl;
        if (n < N_) dynT[(size_t)n * 64 + tx] = tile[tx][nl];
    }
}

__global__ void k_deg(const int* __restrict__ dst, int* __restrict__ deg) {
    int e = blockIdx.x * blockDim.x + threadIdx.x;
    if (e < E_) atomicAdd(&deg[dst[e]], 1);
}

// single-block inclusive scan -> row_ptr (exclusive, row_ptr[0]=0)
__global__ __launch_bounds__(1024)
void k_scan(const int* __restrict__ deg, int* __restrict__ row_ptr) {
    __shared__ int buf[1024];
    __shared__ int carry;
    int tid = threadIdx.x;
    if (tid == 0) { carry = 0; row_ptr[0] = 0; }
    __syncthreads();
    for (int base = 0; base < N_; base += 1024) {
        int i = base + tid;
        int v = (i < N_) ? deg[i] : 0;
        buf[tid] = v;
        __syncthreads();
        for (int off = 1; off < 1024; off <<= 1) {
            int t = (tid >= off) ? buf[tid - off] : 0;
            __syncthreads();
            buf[tid] += t;
            __syncthreads();
        }
        if (i < N_) row_ptr[i + 1] = carry + buf[tid];
        __syncthreads();
        if (tid == 0) carry += buf[1023];
        __syncthreads();
    }
}

__global__ __launch_bounds__(256)
void k_node_init(const int* __restrict__ deg,
                 const float* __restrict__ statics,   // [N,6]
                 const float* __restrict__ w0,        // [7,32]
                 float* __restrict__ dinv,
                 float* __restrict__ selfn,
                 float* __restrict__ h0s) {           // [N,32]
    int n = blockIdx.x * blockDim.x + threadIdx.x;
    if (n >= N_) return;
    float d  = (float)deg[n] + 1.0f;     // + self loop
    float di = rsqrtf(d);
    dinv[n] = di;
    selfn[n] = di * di;
    float s[6];
#pragma unroll
    for (int j = 0; j < 6; ++j) s[j] = statics[n * 6 + j];
#pragma unroll
    for (int k = 0; k < GH_; ++k) {
        float v = 0.0f;
#pragma unroll
        for (int j = 0; j < 6; ++j) v += s[j] * w0[(1 + j) * GH_ + k];
        h0s[n * GH_ + k] = v;
    }
}

__global__ void k_scatter(const int* __restrict__ src, const int* __restrict__ dst,
                          const float* __restrict__ dinv,
                          const int* __restrict__ row_ptr, int* __restrict__ cursor,
                          int* __restrict__ csr_src, float* __restrict__ csr_nm) {
    int e = blockIdx.x * blockDim.x + threadIdx.x;
    if (e >= E_) return;
    int s = src[e], d = dst[e];
    int pos = row_ptr[d] + atomicAdd(&cursor[d], 1);
    csr_src[pos] = s;
    csr_nm[pos]  = dinv[s] * dinv[d];
}

// combined GRU weight matrix, transposed: wT[k][m], k<32 -> wih, k>=32 -> whh
__global__ void k_wt(const float* __restrict__ wih, const float* __restrict__ whh,
                     float* __restrict__ wT) {
    int idx = blockIdx.x * 256 + threadIdx.x;
    if (idx >= 96 * 192) return;
    int k = idx / 192, m = idx % 192;
    wT[idx] = (k < 32) ? wih[m * 32 + k] : whh[m * 64 + (k - 32)];
}

// aT[n][t] = selfn[n]*dynT[n][t] + sum_e nm*dynT[src][t]   (wave per node, lane=t)
__global__ __launch_bounds__(256)
void k_aall(const int* __restrict__ row_ptr, const int* __restrict__ csr_src,
            const float* __restrict__ csr_nm, const float* __restrict__ selfn,
            const float* __restrict__ dynT, float* __restrict__ aT) {
    int gid = blockIdx.x * 256 + threadIdx.x;
    int n = gid >> 6, lane = gid & 63;
    if (n >= N_) return;
    float acc = selfn[n] * dynT[(size_t)n * 64 + lane];
    int e0 = row_ptr[n], e1 = row_ptr[n + 1];
    for (int e = e0; e < e1; ++e) {
        acc += csr_nm[e] * dynT[(size_t)csr_src[e] * 64 + lane];
    }
    aT[(size_t)n * 64 + lane] = acc;
}

// out[n][:] = selfn[n]*feat[n][:] + sum_e nm*feat[src][:]  (8 lanes/node, float4)
// if dorelu: out = relu(agg + bias)
__global__ __launch_bounds__(256)
void k_gather32(const int* __restrict__ row_ptr, const int* __restrict__ csr_src,
                const float* __restrict__ csr_nm, const float* __restrict__ selfn,
                const float* __restrict__ feat, float* __restrict__ out,
                const float* __restrict__ bias, int dorelu) {
    int gid = blockIdx.x * 256 + threadIdx.x;
    int n = gid >> 3, q = gid & 7;
    if (n >= N_) return;
    const float4* f4 = (const float4*)feat;
    float4 acc = f4[n * 8 + q];
    float sn = selfn[n];
    acc.x *= sn; acc.y *= sn; acc.z *= sn; acc.w *= sn;
    int e0 = row_ptr[n], e1 = row_ptr[n + 1];
    for (int e = e0; e < e1; ++e) {
        int s = csr_src[e];
        float nm = csr_nm[e];
        float4 v = f4[s * 8 + q];
        acc.x += nm * v.x; acc.y += nm * v.y; acc.z += nm * v.z; acc.w += nm * v.w;
    }
    if (dorelu) {
        float4 b = ((const float4*)bias)[q];
        acc.x = fmaxf(acc.x + b.x, 0.0f);
        acc.y = fmaxf(acc.y + b.y, 0.0f);
        acc.z = fmaxf(acc.z + b.z, 0.0f);
        acc.w = fmaxf(acc.w + b.w, 0.0f);
    }
    ((float4*)out)[n * 8 + q] = acc;
}

// ---------- per-timestep ----------
__global__ __launch_bounds__(256)
void k_transform(const float* __restrict__ aT, int t,
                 const float* __restrict__ csagg,
                 const float* __restrict__ w0,      // row 0 used
                 const float* __restrict__ b0,
                 const float* __restrict__ w1,      // [32,32]
                 float* __restrict__ g1) {
    int n = blockIdx.x * blockDim.x + threadIdx.x;
    if (n >= N_) return;
    float av = aT[(size_t)n * 64 + t];
    float h1[GH_];
#pragma unroll
    for (int k = 0; k < GH_; ++k) {
        float v = av * w0[k] + csagg[n * GH_ + k] + b0[k];
        h1[k] = v > 0.0f ? v : 0.0f;
    }
#pragma unroll
    for (int j = 0; j < GH_; ++j) {
        float v = 0.0f;
#pragma unroll
        for (int k = 0; k < GH_; ++k) v += h1[k] * w1[k * GH_ + j];
        g1[n * GH_ + j] = v;
    }
}

// GRU as register-blocked GEMM: lane j owns output row j (3 gates),
// wave processes 16 nodes; activations via wave-uniform scalar loads.
__global__ __launch_bounds__(256)
void k_gru2(const float* __restrict__ xA,    // [N,32] = relu(agg2+b1)
            const float* __restrict__ wT,    // [96][192]
            const float* __restrict__ bih, const float* __restrict__ bhh,
            float* __restrict__ hA) {        // [N,64] node-major state
    int j = threadIdx.x & 63;
    int wv = __builtin_amdgcn_readfirstlane(threadIdx.x >> 6);
    int nb = blockIdx.x * 64 + wv * 16;
    if (nb >= N_) return;                    // N % 16 == 0, active waves in-bounds
    float accr[16], accz[16], accnx[16], accnh[16];
#pragma unroll
    for (int i = 0; i < 16; ++i) { accr[i] = 0; accz[i] = 0; accnx[i] = 0; accnh[i] = 0; }
    const float* xb = xA + (size_t)nb * GH_;
    const float* hb = hA + (size_t)nb * RH_;
#pragma unroll 4
    for (int k = 0; k < 32; ++k) {           // x-part of K
        float wr = wT[k * 192 + j];
        float wz = wT[k * 192 + 64 + j];
        float wn = wT[k * 192 + 128 + j];
#pragma unroll
        for (int i = 0; i < 16; ++i) {
            float xv = xb[i * GH_ + k];      // wave-uniform -> s_load
            accr[i] += wr * xv; accz[i] += wz * xv; accnx[i] += wn * xv;
        }
    }
#pragma unroll 2
    for (int k = 0; k < 64; ++k) {           // h-part of K
        float wr = wT[(32 + k) * 192 + j];
        float wz = wT[(32 + k) * 192 + 64 + j];
        float wn = wT[(32 + k) * 192 + 128 + j];
#pragma unroll
        for (int i = 0; i < 16; ++i) {
            float hv = hb[i * RH_ + k];      // wave-uniform -> s_load
            accr[i] += wr * hv; accz[i] += wz * hv; accnh[i] += wn * hv;
        }
    }
    float br  = bih[j] + bhh[j];
    float bz  = bih[64 + j] + bhh[64 + j];
    float bnx = bih[128 + j];
    float bnh = bhh[128 + j];
#pragma unroll
    for (int i = 0; i < 16; ++i) {
        float h_old = hb[i * RH_ + j];
        float r = fast_sigmoid(accr[i] + br);
        float z = fast_sigmoid(accz[i] + bz);
        float c = fast_tanh(accnx[i] + bnx + r * (accnh[i] + bnh));
        hA[(size_t)(nb + i) * RH_ + j] = (1.0f - z) * c + z * h_old;
    }
}

__global__ __launch_bounds__(256)
void k_mlp(const float* __restrict__ hA, const float* __restrict__ w1,
           const float* __restrict__ b1, const float* __restrict__ w2,
           const float* __restrict__ b2, float* __restrict__ out) {
    int n = blockIdx.x * blockDim.x + threadIdx.x;
    if (n >= N_) return;
    float h[RH_];
    const float4* h4 = (const float4*)(hA + (size_t)n * RH_);
#pragma unroll
    for (int q = 0; q < 16; ++q) {
        float4 v = h4[q];
        h[q * 4 + 0] = v.x; h[q * 4 + 1] = v.y; h[q * 4 + 2] = v.z; h[q * 4 + 3] = v.w;
    }
    float acc = b2[0];
#pragma unroll 1
    for (int j = 0; j < RH_; ++j) {
        float v = b1[j];
#pragma unroll
        for (int k = 0; k < RH_; ++k) v += w1[j * RH_ + k] * h[k];
        v = v > 0.0f ? v : 0.0f;
        acc += w2[j] * v;
    }
    out[n] = acc;
}

extern "C" void kernel_launch(void* const* d_in, const int* in_sizes, int n_in,
                              void* d_out, int out_size, void* d_ws, size_t ws_size,
                              hipStream_t stream) {
    const float* dyn     = (const float*)d_in[0];
    const float* statics = (const float*)d_in[1];
    const int*   ei      = (const int*)d_in[2];
    const float* w0      = (const float*)d_in[3];
    const float* b0      = (const float*)d_in[4];
    const float* w1      = (const float*)d_in[5];
    const float* b1      = (const float*)d_in[6];
    const float* wih     = (const float*)d_in[7];
    const float* whh     = (const float*)d_in[8];
    const float* bih     = (const float*)d_in[9];
    const float* bhh     = (const float*)d_in[10];
    const float* mw1     = (const float*)d_in[11];
    const float* mb1     = (const float*)d_in[12];
    const float* mw2     = (const float*)d_in[13];
    const float* mb2     = (const float*)d_in[14];
    const int* src = ei;
    const int* dst = ei + E_;

    char* ws = (char*)d_ws;
    auto alloc = [&](size_t elems) { void* p = ws; ws += elems * 4; return p; };
    int*   deg     = (int*)alloc(N_);
    int*   row_ptr = (int*)alloc(N_ + 4);
    int*   cursor  = (int*)alloc(N_);
    int*   csr_src = (int*)alloc(E_);
    float* csr_nm  = (float*)alloc(E_);
    float* dinv    = (float*)alloc(N_);
    float* selfn   = (float*)alloc(N_);
    float* h0s     = (float*)alloc(32 * N_);
    float* csagg   = (float*)alloc(32 * N_);
    float* g1      = (float*)alloc(32 * N_);
    float* xA      = (float*)alloc(32 * N_);
    float* hA      = (float*)alloc(64 * N_);
    float* dynT    = (float*)alloc(64 * N_);
    float* aT      = (float*)alloc(64 * N_);
    float* wT      = (float*)alloc(96 * 192);

    auto cdiv = [](long long x, int b) { return (unsigned)((x + b - 1) / b); };
    const int B = 256;

    hipMemsetAsync(deg, 0, N_ * sizeof(int), stream);
    hipMemsetAsync(cursor, 0, N_ * sizeof(int), stream);
    hipMemsetAsync(hA, 0, (size_t)RH_ * N_ * sizeof(float), stream);

    k_transpose<<<cdiv(N_, 64), dim3(64, 4), 0, stream>>>(dyn, dynT);
    k_deg<<<cdiv(E_, B), B, 0, stream>>>(dst, deg);
    k_scan<<<1, 1024, 0, stream>>>(deg, row_ptr);
    k_node_init<<<cdiv(N_, B), B, 0, stream>>>(deg, statics, w0, dinv, selfn, h0s);
    k_scatter<<<cdiv(E_, B), B, 0, stream>>>(src, dst, dinv, row_ptr, cursor,
                                             csr_src, csr_nm);
    k_wt<<<cdiv(96 * 192, B), B, 0, stream>>>(wih, whh, wT);
    k_gather32<<<cdiv((long long)N_ * 8, B), B, 0, stream>>>(row_ptr, csr_src, csr_nm,
                                                             selfn, h0s, csagg,
                                                             (const float*)nullptr, 0);
    k_aall<<<cdiv((long long)N_ * 64, B), B, 0, stream>>>(row_ptr, csr_src, csr_nm,
                                                          selfn, dynT, aT);

    for (int t = 0; t < T_; ++t) {
        k_transform<<<cdiv(N_, B), B, 0, stream>>>(aT, t, csagg, w0, b0, w1, g1);
        k_gather32<<<cdiv((long long)N_ * 8, B), B, 0, stream>>>(row_ptr, csr_src,
                                                                 csr_nm, selfn, g1, xA,
                                                                 b1, 1);
        k_gru2<<<cdiv(N_, 64), B, 0, stream>>>(xA, wT, bih, bhh, hA);
    }
    k_mlp<<<cdiv(N_, B), B, 0, stream>>>(hA, mw1, mb1, mw2, mb2, (float*)d_out);
}

// Round 4
// 5660.528 us; speedup vs baseline: 12.1595x; 1.3951x over previous
//
#include <hip/hip_runtime.h>
#include <hip/hip_bf16.h>

#define T_   64
#define N_   50000
#define E_   1600000
#define GH_  32
#define RH_  64

#define GRU_BLOCKS_ 782            // cdiv(N,64), 64 nodes/block (4 waves x 16)
#define TR_BLOCKS_  196            // cdiv(N,256)

typedef _Float16 half_t;
typedef __attribute__((ext_vector_type(8))) _Float16 half8;

static __device__ __forceinline__ float fast_sigmoid(float v) {
    float e = __expf(-v);
    return __builtin_amdgcn_rcpf(1.0f + e);
}
static __device__ __forceinline__ float fast_tanh(float v) {
    return 2.0f * fast_sigmoid(2.0f * v) - 1.0f;
}

// ---------- prologue ----------

// dyn [T,N] -> dynT [N,T]
__global__ __launch_bounds__(256)
void k_transpose(const float* __restrict__ dyn, float* __restrict__ dynT) {
    __shared__ float tile[64][65];
    int n0 = blockIdx.x * 64;
    int tx = threadIdx.x, ty = threadIdx.y;
#pragma unroll
    for (int r = 0; r < 16; ++r) {
        int t = r * 4 + ty;
        int n = n0 + tx;
        tile[t][tx] = (n < N_) ? dyn[(size_t)t * N_ + n] : 0.0f;
    }
    __syncthreads();
#pragma unroll
    for (int r = 0; r < 16; ++r) {
        int nl = r * 4 + ty;
        int n = n0 + nl;
        if (n < N_) dynT[(size_t)n * 64 + tx] = tile[tx][nl];
    }
}

// aT [N,64] -> aTt [64,N]
__global__ __launch_bounds__(256)
void k_trB(const float* __restrict__ in, float* __restrict__ out) {
    __shared__ float tile[64][65];
    int n0 = blockIdx.x * 64;
    int tx = threadIdx.x, ty = threadIdx.y;
#pragma unroll
    for (int r = 0; r < 16; ++r) {
        int nl = r * 4 + ty;
        int n = n0 + nl;
        tile[nl][tx] = (n < N_) ? in[(size_t)n * 64 + tx] : 0.0f;
    }
    __syncthreads();
#pragma unroll
    for (int r = 0; r < 16; ++r) {
        int t = r * 4 + ty;
        int n = n0 + tx;
        if (n < N_) out[(size_t)t * N_ + n] = tile[tx][t];
    }
}

__global__ void k_deg(const int* __restrict__ dst, int* __restrict__ deg) {
    int e = blockIdx.x * blockDim.x + threadIdx.x;
    if (e < E_) atomicAdd(&deg[dst[e]], 1);
}

__global__ __launch_bounds__(1024)
void k_scan(const int* __restrict__ deg, int* __restrict__ row_ptr) {
    __shared__ int buf[1024];
    __shared__ int carry;
    int tid = threadIdx.x;
    if (tid == 0) { carry = 0; row_ptr[0] = 0; }
    __syncthreads();
    for (int base = 0; base < N_; base += 1024) {
        int i = base + tid;
        int v = (i < N_) ? deg[i] : 0;
        buf[tid] = v;
        __syncthreads();
        for (int off = 1; off < 1024; off <<= 1) {
            int t = (tid >= off) ? buf[tid - off] : 0;
            __syncthreads();
            buf[tid] += t;
            __syncthreads();
        }
        if (i < N_) row_ptr[i + 1] = carry + buf[tid];
        __syncthreads();
        if (tid == 0) carry += buf[1023];
        __syncthreads();
    }
}

__global__ __launch_bounds__(256)
void k_node_init(const int* __restrict__ deg,
                 const float* __restrict__ statics,
                 const float* __restrict__ w0,
                 float* __restrict__ dinv,
                 float* __restrict__ selfn,
                 float* __restrict__ h0s) {
    int n = blockIdx.x * blockDim.x + threadIdx.x;
    if (n >= N_) return;
    float d  = (float)deg[n] + 1.0f;
    float di = rsqrtf(d);
    dinv[n] = di;
    selfn[n] = di * di;
    float s[6];
#pragma unroll
    for (int j = 0; j < 6; ++j) s[j] = statics[n * 6 + j];
#pragma unroll
    for (int k = 0; k < GH_; ++k) {
        float v = 0.0f;
#pragma unroll
        for (int j = 0; j < 6; ++j) v += s[j] * w0[(1 + j) * GH_ + k];
        h0s[n * GH_ + k] = v;
    }
}

__global__ void k_scatter(const int* __restrict__ src, const int* __restrict__ dst,
                          const float* __restrict__ dinv,
                          const int* __restrict__ row_ptr, int* __restrict__ cursor,
                          int* __restrict__ csr_src, float* __restrict__ csr_nm) {
    int e = blockIdx.x * blockDim.x + threadIdx.x;
    if (e >= E_) return;
    int s = src[e], d = dst[e];
    int pos = row_ptr[d] + atomicAdd(&cursor[d], 1);
    csr_src[pos] = s;
    csr_nm[pos]  = dinv[s] * dinv[d];
}

__global__ void k_wt(const float* __restrict__ wih, const float* __restrict__ whh,
                     float* __restrict__ wT) {
    int idx = blockIdx.x * 256 + threadIdx.x;
    if (idx >= 96 * 192) return;
    int k = idx / 192, m = idx % 192;
    wT[idx] = (k < 32) ? wih[m * 32 + k] : whh[m * 64 + (k - 32)];
}

// aT[n][t], wave per node, lane=t, edge loop unrolled x4
__global__ __launch_bounds__(256)
void k_aall(const int* __restrict__ row_ptr, const int* __restrict__ csr_src,
            const float* __restrict__ csr_nm, const float* __restrict__ selfn,
            const float* __restrict__ dynT, float* __restrict__ aT) {
    int gid = blockIdx.x * 256 + threadIdx.x;
    int n = gid >> 6, lane = gid & 63;
    if (n >= N_) return;
    float acc = selfn[n] * dynT[(size_t)n * 64 + lane];
    int e0 = row_ptr[n], e1 = row_ptr[n + 1];
    int e = e0;
    for (; e < e1 && (e & 3); ++e)
        acc += csr_nm[e] * dynT[(size_t)csr_src[e] * 64 + lane];
    for (; e + 4 <= e1; e += 4) {
        int4 ss   = *(const int4*)(csr_src + e);
        float4 nm = *(const float4*)(csr_nm + e);
        float v0 = dynT[(size_t)ss.x * 64 + lane];
        float v1 = dynT[(size_t)ss.y * 64 + lane];
        float v2 = dynT[(size_t)ss.z * 64 + lane];
        float v3 = dynT[(size_t)ss.w * 64 + lane];
        acc += nm.x * v0 + nm.y * v1 + nm.z * v2 + nm.w * v3;
    }
    for (; e < e1; ++e)
        acc += csr_nm[e] * dynT[(size_t)csr_src[e] * 64 + lane];
    aT[(size_t)n * 64 + lane] = acc;
}

// fp32 gather (one-time, for csagg): 8 lanes/node, float4
__global__ __launch_bounds__(256)
void k_gather32f(const int* __restrict__ row_ptr, const int* __restrict__ csr_src,
                 const float* __restrict__ csr_nm, const float* __restrict__ selfn,
                 const float* __restrict__ feat, float* __restrict__ out) {
    int gid = blockIdx.x * 256 + threadIdx.x;
    int n = gid >> 3, q = gid & 7;
    if (n >= N_) return;
    const float4* f4 = (const float4*)feat;
    float4 acc = f4[n * 8 + q];
    float sn = selfn[n];
    acc.x *= sn; acc.y *= sn; acc.z *= sn; acc.w *= sn;
    int e0 = row_ptr[n], e1 = row_ptr[n + 1];
    for (int e = e0; e < e1; ++e) {
        int s = csr_src[e];
        float nm = csr_nm[e];
        float4 v = f4[s * 8 + q];
        acc.x += nm * v.x; acc.y += nm * v.y; acc.z += nm * v.z; acc.w += nm * v.w;
    }
    ((float4*)out)[n * 8 + q] = acc;
}

// fp16 gather (per-t): 4 lanes/node, half8 loads, edge loop unrolled x4,
// fused relu(agg + b1) epilogue -> xA fp32
__global__ __launch_bounds__(256)
void k_gather16(const int* __restrict__ row_ptr, const int* __restrict__ csr_src,
                const float* __restrict__ csr_nm, const float* __restrict__ selfn,
                const half_t* __restrict__ g1h, float* __restrict__ xA,
                const float* __restrict__ b1) {
    int gid = blockIdx.x * 256 + threadIdx.x;
    int n = gid >> 2, q = gid & 3;
    if (n >= N_) return;
    const half8* f8 = (const half8*)g1h;
    float acc[8];
    half8 sv = f8[(size_t)n * 4 + q];
    float sn = selfn[n];
#pragma unroll
    for (int i = 0; i < 8; ++i) acc[i] = sn * (float)sv[i];
    int e0 = row_ptr[n], e1 = row_ptr[n + 1];
    int e = e0;
    for (; e < e1 && (e & 3); ++e) {
        int s = csr_src[e]; float nm = csr_nm[e];
        half8 v = f8[(size_t)s * 4 + q];
#pragma unroll
        for (int i = 0; i < 8; ++i) acc[i] += nm * (float)v[i];
    }
    for (; e + 4 <= e1; e += 4) {
        int4 ss   = *(const int4*)(csr_src + e);
        float4 nm = *(const float4*)(csr_nm + e);
        half8 v0 = f8[(size_t)ss.x * 4 + q];
        half8 v1 = f8[(size_t)ss.y * 4 + q];
        half8 v2 = f8[(size_t)ss.z * 4 + q];
        half8 v3 = f8[(size_t)ss.w * 4 + q];
#pragma unroll
        for (int i = 0; i < 8; ++i)
            acc[i] += nm.x * (float)v0[i] + nm.y * (float)v1[i]
                    + nm.z * (float)v2[i] + nm.w * (float)v3[i];
    }
    for (; e < e1; ++e) {
        int s = csr_src[e]; float nm = csr_nm[e];
        half8 v = f8[(size_t)s * 4 + q];
#pragma unroll
        for (int i = 0; i < 8; ++i) acc[i] += nm * (float)v[i];
    }
    float4 o0, o1;
    const float* bb = b1 + q * 8;
    o0.x = fmaxf(acc[0] + bb[0], 0.0f); o0.y = fmaxf(acc[1] + bb[1], 0.0f);
    o0.z = fmaxf(acc[2] + bb[2], 0.0f); o0.w = fmaxf(acc[3] + bb[3], 0.0f);
    o1.x = fmaxf(acc[4] + bb[4], 0.0f); o1.y = fmaxf(acc[5] + bb[5], 0.0f);
    o1.z = fmaxf(acc[6] + bb[6], 0.0f); o1.w = fmaxf(acc[7] + bb[7], 0.0f);
    float4* out = (float4*)(xA + (size_t)n * GH_ + q * 8);
    out[0] = o0; out[1] = o1;
}

// ---------- per-timestep device bodies ----------

static __device__ __forceinline__
void tr_body(int bid, int t, const float* __restrict__ aTt,
             const float* __restrict__ csagg, const float* __restrict__ w0,
             const float* __restrict__ b0, const float* __restrict__ w1,
             half_t* __restrict__ g1h) {
    int n = bid * 256 + threadIdx.x;
    if (n >= N_) return;
    float av = aTt[(size_t)t * N_ + n];
    float h1[GH_];
#pragma unroll
    for (int k = 0; k < GH_; ++k) {
        float v = av * w0[k] + csagg[(size_t)n * GH_ + k] + b0[k];
        h1[k] = v > 0.0f ? v : 0.0f;
    }
    half8 o[4];
#pragma unroll
    for (int j = 0; j < GH_; ++j) {
        float v = 0.0f;
#pragma unroll
        for (int k = 0; k < GH_; ++k) v += h1[k] * w1[k * GH_ + j];
        o[j >> 3][j & 7] = (half_t)v;
    }
    half8* dst = (half8*)(g1h + (size_t)n * GH_);
#pragma unroll
    for (int c = 0; c < 4; ++c) dst[c] = o[c];
}

static __device__ __forceinline__
void gru_body(int bid, const float* __restrict__ xA, const float* __restrict__ wT,
              const float* __restrict__ bih, const float* __restrict__ bhh,
              float* __restrict__ hA) {
    int j = threadIdx.x & 63;
    int wv = __builtin_amdgcn_readfirstlane(threadIdx.x >> 6);
    int nb = bid * 64 + wv * 16;
    if (nb >= N_) return;
    float accr[16], accz[16], accnx[16], accnh[16];
#pragma unroll
    for (int i = 0; i < 16; ++i) { accr[i] = 0; accz[i] = 0; accnx[i] = 0; accnh[i] = 0; }
    const float* xb = xA + (size_t)nb * GH_;
    const float* hb = hA + (size_t)nb * RH_;
#pragma unroll 4
    for (int k = 0; k < 32; ++k) {
        float wr = wT[k * 192 + j];
        float wz = wT[k * 192 + 64 + j];
        float wn = wT[k * 192 + 128 + j];
#pragma unroll
        for (int i = 0; i < 16; ++i) {
            float xv = xb[i * GH_ + k];
            accr[i] += wr * xv; accz[i] += wz * xv; accnx[i] += wn * xv;
        }
    }
#pragma unroll 2
    for (int k = 0; k < 64; ++k) {
        float wr = wT[(32 + k) * 192 + j];
        float wz = wT[(32 + k) * 192 + 64 + j];
        float wn = wT[(32 + k) * 192 + 128 + j];
#pragma unroll
        for (int i = 0; i < 16; ++i) {
            float hv = hb[i * RH_ + k];
            accr[i] += wr * hv; accz[i] += wz * hv; accnh[i] += wn * hv;
        }
    }
    float br  = bih[j] + bhh[j];
    float bz  = bih[64 + j] + bhh[64 + j];
    float bnx = bih[128 + j];
    float bnh = bhh[128 + j];
#pragma unroll
    for (int i = 0; i < 16; ++i) {
        float h_old = hb[i * RH_ + j];
        float r = fast_sigmoid(accr[i] + br);
        float z = fast_sigmoid(accz[i] + bz);
        float c = fast_tanh(accnx[i] + bnx + r * (accnh[i] + bnh));
        hA[(size_t)(nb + i) * RH_ + j] = (1.0f - z) * c + z * h_old;
    }
}

// t=0 transform only
__global__ __launch_bounds__(256)
void k_tr0(const float* __restrict__ aTt, const float* __restrict__ csagg,
           const float* __restrict__ w0, const float* __restrict__ b0,
           const float* __restrict__ w1, half_t* __restrict__ g1h) {
    tr_body(blockIdx.x, 0, aTt, csagg, w0, b0, w1, g1h);
}

// fused: gru(t) on blocks [0,GRU_BLOCKS), transform(t+1) on the rest
__global__ __launch_bounds__(256)
void k_gru_tr(const float* __restrict__ xA, const float* __restrict__ wT,
              const float* __restrict__ bih, const float* __restrict__ bhh,
              float* __restrict__ hA,
              const float* __restrict__ aTt, int tnext,
              const float* __restrict__ csagg, const float* __restrict__ w0,
              const float* __restrict__ b0, const float* __restrict__ w1,
              half_t* __restrict__ g1h) {
    if ((int)blockIdx.x < GRU_BLOCKS_)
        gru_body(blockIdx.x, xA, wT, bih, bhh, hA);
    else
        tr_body(blockIdx.x - GRU_BLOCKS_, tnext, aTt, csagg, w0, b0, w1, g1h);
}

__global__ __launch_bounds__(256)
void k_mlp(const float* __restrict__ hA, const float* __restrict__ w1,
           const float* __restrict__ b1, const float* __restrict__ w2,
           const float* __restrict__ b2, float* __restrict__ out) {
    int n = blockIdx.x * blockDim.x + threadIdx.x;
    if (n >= N_) return;
    float h[RH_];
    const float4* h4 = (const float4*)(hA + (size_t)n * RH_);
#pragma unroll
    for (int q = 0; q < 16; ++q) {
        float4 v = h4[q];
        h[q * 4 + 0] = v.x; h[q * 4 + 1] = v.y; h[q * 4 + 2] = v.z; h[q * 4 + 3] = v.w;
    }
    float acc = b2[0];
#pragma unroll 1
    for (int j = 0; j < RH_; ++j) {
        float v = b1[j];
#pragma unroll
        for (int k = 0; k < RH_; ++k) v += w1[j * RH_ + k] * h[k];
        v = v > 0.0f ? v : 0.0f;
        acc += w2[j] * v;
    }
    out[n] = acc;
}

extern "C" void kernel_launch(void* const* d_in, const int* in_sizes, int n_in,
                              void* d_out, int out_size, void* d_ws, size_t ws_size,
                              hipStream_t stream) {
    const float* dyn     = (const float*)d_in[0];
    const float* statics = (const float*)d_in[1];
    const int*   ei      = (const int*)d_in[2];
    const float* w0      = (const float*)d_in[3];
    const float* b0      = (const float*)d_in[4];
    const float* w1      = (const float*)d_in[5];
    const float* b1      = (const float*)d_in[6];
    const float* wih     = (const float*)d_in[7];
    const float* whh     = (const float*)d_in[8];
    const float* bih     = (const float*)d_in[9];
    const float* bhh     = (const float*)d_in[10];
    const float* mw1     = (const float*)d_in[11];
    const float* mb1     = (const float*)d_in[12];
    const float* mw2     = (const float*)d_in[13];
    const float* mb2     = (const float*)d_in[14];
    const int* src = ei;
    const int* dst = ei + E_;

    char* ws = (char*)d_ws;
    auto alloc = [&](size_t elems) { void* p = ws; ws += elems * 4; return p; };
    int*    deg     = (int*)alloc(N_);
    int*    row_ptr = (int*)alloc(N_ + 4);
    int*    cursor  = (int*)alloc(N_);
    int*    csr_src = (int*)alloc(E_);
    float*  csr_nm  = (float*)alloc(E_);
    float*  dinv    = (float*)alloc(N_);
    float*  selfn   = (float*)alloc(N_);
    float*  h0s     = (float*)alloc(32 * N_);
    float*  csagg   = (float*)alloc(32 * N_);
    half_t* g1h     = (half_t*)alloc(16 * N_);   // [N,32] fp16
    float*  xA      = (float*)alloc(32 * N_);
    float*  hA      = (float*)alloc(64 * N_);
    float*  dynT    = (float*)alloc(64 * N_);
    float*  aT      = (float*)alloc(64 * N_);
    float*  aTt     = (float*)alloc(64 * N_);
    float*  wT      = (float*)alloc(96 * 192);

    auto cdiv = [](long long x, int b) { return (unsigned)((x + b - 1) / b); };
    const int B = 256;

    hipMemsetAsync(deg, 0, N_ * sizeof(int), stream);
    hipMemsetAsync(cursor, 0, N_ * sizeof(int), stream);
    hipMemsetAsync(hA, 0, (size_t)RH_ * N_ * sizeof(float), stream);

    k_transpose<<<cdiv(N_, 64), dim3(64, 4), 0, stream>>>(dyn, dynT);
    k_deg<<<cdiv(E_, B), B, 0, stream>>>(dst, deg);
    k_scan<<<1, 1024, 0, stream>>>(deg, row_ptr);
    k_node_init<<<cdiv(N_, B), B, 0, stream>>>(deg, statics, w0, dinv, selfn, h0s);
    k_scatter<<<cdiv(E_, B), B, 0, stream>>>(src, dst, dinv, row_ptr, cursor,
                                             csr_src, csr_nm);
    k_wt<<<cdiv(96 * 192, B), B, 0, stream>>>(wih, whh, wT);
    k_gather32f<<<cdiv((long long)N_ * 8, B), B, 0, stream>>>(row_ptr, csr_src, csr_nm,
                                                              selfn, h0s, csagg);
    k_aall<<<cdiv((long long)N_ * 64, B), B, 0, stream>>>(row_ptr, csr_src, csr_nm,
                                                          selfn, dynT, aT);
    k_trB<<<cdiv(N_, 64), dim3(64, 4), 0, stream>>>(aT, aTt);

    k_tr0<<<TR_BLOCKS_, B, 0, stream>>>(aTt, csagg, w0, b0, w1, g1h);
    for (int t = 0; t < T_; ++t) {
        k_gather16<<<cdiv((long long)N_ * 4, B), B, 0, stream>>>(row_ptr, csr_src,
                                                                 csr_nm, selfn, g1h,
                                                                 xA, b1);
        unsigned grid = GRU_BLOCKS_ + ((t + 1 < T_) ? TR_BLOCKS_ : 0);
        k_gru_tr<<<grid, B, 0, stream>>>(xA, wT, bih, bhh, hA,
                                         aTt, t + 1, csagg, w0, b0, w1, g1h);
    }
    k_mlp<<<cdiv(N_, B), B, 0, stream>>>(hA, mw1, mb1, mw2, mb2, (float*)d_out);
}

// Round 5
// 5652.840 us; speedup vs baseline: 12.1760x; 1.0014x over previous
//
#include <hip/hip_runtime.h>
#include <hip/hip_bf16.h>

#define T_   64
#define N_   50000
#define E_   1600000
#define GH_  32
#define RH_  64

#define GRU_BLOCKS_ 782            // cdiv(N,64): 64 nodes/block (4 waves x 16)
#define TR_BLOCKS_  196            // cdiv(N,256)
#define XL_STRIDE_  36             // LDS row stride (floats): 16B-aligned, <=2-way banks

typedef _Float16 half_t;
typedef __attribute__((ext_vector_type(8))) _Float16 half8;

static __device__ __forceinline__ float fast_sigmoid(float v) {
    float e = __expf(-v);
    return __builtin_amdgcn_rcpf(1.0f + e);
}
static __device__ __forceinline__ float fast_tanh(float v) {
    return 2.0f * fast_sigmoid(2.0f * v) - 1.0f;
}

// ---------- prologue ----------

// dyn [T,N] -> dynT [N,T]
__global__ __launch_bounds__(256)
void k_transpose(const float* __restrict__ dyn, float* __restrict__ dynT) {
    __shared__ float tile[64][65];
    int n0 = blockIdx.x * 64;
    int tx = threadIdx.x, ty = threadIdx.y;
#pragma unroll
    for (int r = 0; r < 16; ++r) {
        int t = r * 4 + ty;
        int n = n0 + tx;
        tile[t][tx] = (n < N_) ? dyn[(size_t)t * N_ + n] : 0.0f;
    }
    __syncthreads();
#pragma unroll
    for (int r = 0; r < 16; ++r) {
        int nl = r * 4 + ty;
        int n = n0 + nl;
        if (n < N_) dynT[(size_t)n * 64 + tx] = tile[tx][nl];
    }
}

// aT [N,64] -> aTt [64,N]
__global__ __launch_bounds__(256)
void k_trB(const float* __restrict__ in, float* __restrict__ out) {
    __shared__ float tile[64][65];
    int n0 = blockIdx.x * 64;
    int tx = threadIdx.x, ty = threadIdx.y;
#pragma unroll
    for (int r = 0; r < 16; ++r) {
        int nl = r * 4 + ty;
        int n = n0 + nl;
        tile[nl][tx] = (n < N_) ? in[(size_t)n * 64 + tx] : 0.0f;
    }
    __syncthreads();
#pragma unroll
    for (int r = 0; r < 16; ++r) {
        int t = r * 4 + ty;
        int n = n0 + tx;
        if (n < N_) out[(size_t)t * N_ + n] = tile[tx][t];
    }
}

__global__ void k_deg(const int* __restrict__ dst, int* __restrict__ deg) {
    int e = blockIdx.x * blockDim.x + threadIdx.x;
    if (e < E_) atomicAdd(&deg[dst[e]], 1);
}

__global__ __launch_bounds__(1024)
void k_scan(const int* __restrict__ deg, int* __restrict__ row_ptr) {
    __shared__ int buf[1024];
    __shared__ int carry;
    int tid = threadIdx.x;
    if (tid == 0) { carry = 0; row_ptr[0] = 0; }
    __syncthreads();
    for (int base = 0; base < N_; base += 1024) {
        int i = base + tid;
        int v = (i < N_) ? deg[i] : 0;
        buf[tid] = v;
        __syncthreads();
        for (int off = 1; off < 1024; off <<= 1) {
            int t = (tid >= off) ? buf[tid - off] : 0;
            __syncthreads();
            buf[tid] += t;
            __syncthreads();
        }
        if (i < N_) row_ptr[i + 1] = carry + buf[tid];
        __syncthreads();
        if (tid == 0) carry += buf[1023];
        __syncthreads();
    }
}

__global__ __launch_bounds__(256)
void k_node_init(const int* __restrict__ deg,
                 const float* __restrict__ statics,
                 const float* __restrict__ w0,
                 float* __restrict__ dinv,
                 float* __restrict__ selfn,
                 float* __restrict__ h0s) {
    int n = blockIdx.x * blockDim.x + threadIdx.x;
    if (n >= N_) return;
    float d  = (float)deg[n] + 1.0f;
    float di = rsqrtf(d);
    dinv[n] = di;
    selfn[n] = di * di;
    float s[6];
#pragma unroll
    for (int j = 0; j < 6; ++j) s[j] = statics[n * 6 + j];
#pragma unroll
    for (int k = 0; k < GH_; ++k) {
        float v = 0.0f;
#pragma unroll
        for (int j = 0; j < 6; ++j) v += s[j] * w0[(1 + j) * GH_ + k];
        h0s[n * GH_ + k] = v;
    }
}

// interleaved 8-byte edge record {src, norm}
__global__ void k_scatter(const int* __restrict__ src, const int* __restrict__ dst,
                          const float* __restrict__ dinv,
                          const int* __restrict__ row_ptr, int* __restrict__ cursor,
                          int2* __restrict__ erec) {
    int e = blockIdx.x * blockDim.x + threadIdx.x;
    if (e >= E_) return;
    int s = src[e], d = dst[e];
    int pos = row_ptr[d] + atomicAdd(&cursor[d], 1);
    erec[pos] = make_int2(s, __float_as_int(dinv[s] * dinv[d]));
}

__global__ void k_wt(const float* __restrict__ wih, const float* __restrict__ whh,
                     float* __restrict__ wT) {
    int idx = blockIdx.x * 256 + threadIdx.x;
    if (idx >= 96 * 192) return;
    int k = idx / 192, m = idx % 192;
    wT[idx] = (k < 32) ? wih[m * 32 + k] : whh[m * 64 + (k - 32)];
}

// aT[n][t], wave per node, lane=t, edge loop unrolled x4
__global__ __launch_bounds__(256)
void k_aall(const int* __restrict__ row_ptr, const int2* __restrict__ erec,
            const float* __restrict__ selfn,
            const float* __restrict__ dynT, float* __restrict__ aT) {
    int gid = blockIdx.x * 256 + threadIdx.x;
    int n = gid >> 6, lane = gid & 63;
    if (n >= N_) return;
    float acc = selfn[n] * dynT[(size_t)n * 64 + lane];
    int e0 = row_ptr[n], e1 = row_ptr[n + 1];
    int e = e0;
    for (; e < e1 && (e & 3); ++e) {
        int2 r = erec[e];
        acc += __int_as_float(r.y) * dynT[(size_t)r.x * 64 + lane];
    }
    for (; e + 4 <= e1; e += 4) {
        int4 p0 = *(const int4*)(erec + e);
        int4 p1 = *(const int4*)(erec + e + 2);
        float v0 = dynT[(size_t)p0.x * 64 + lane];
        float v1 = dynT[(size_t)p0.z * 64 + lane];
        float v2 = dynT[(size_t)p1.x * 64 + lane];
        float v3 = dynT[(size_t)p1.z * 64 + lane];
        acc += __int_as_float(p0.y) * v0 + __int_as_float(p0.w) * v1
             + __int_as_float(p1.y) * v2 + __int_as_float(p1.w) * v3;
    }
    for (; e < e1; ++e) {
        int2 r = erec[e];
        acc += __int_as_float(r.y) * dynT[(size_t)r.x * 64 + lane];
    }
    aT[(size_t)n * 64 + lane] = acc;
}

// fp32 gather (one-time, csagg): 8 lanes/node, float4, unrolled x4
__global__ __launch_bounds__(256)
void k_gather32f(const int* __restrict__ row_ptr, const int2* __restrict__ erec,
                 const float* __restrict__ selfn,
                 const float* __restrict__ feat, float* __restrict__ out) {
    int gid = blockIdx.x * 256 + threadIdx.x;
    int n = gid >> 3, q = gid & 7;
    if (n >= N_) return;
    const float4* f4 = (const float4*)feat;
    float4 acc = f4[n * 8 + q];
    float sn = selfn[n];
    acc.x *= sn; acc.y *= sn; acc.z *= sn; acc.w *= sn;
    int e0 = row_ptr[n], e1 = row_ptr[n + 1];
    int e = e0;
    for (; e < e1 && (e & 3); ++e) {
        int2 r = erec[e];
        float nm = __int_as_float(r.y);
        float4 v = f4[(size_t)r.x * 8 + q];
        acc.x += nm * v.x; acc.y += nm * v.y; acc.z += nm * v.z; acc.w += nm * v.w;
    }
    for (; e + 4 <= e1; e += 4) {
        int4 p0 = *(const int4*)(erec + e);
        int4 p1 = *(const int4*)(erec + e + 2);
        float4 v0 = f4[(size_t)p0.x * 8 + q];
        float4 v1 = f4[(size_t)p0.z * 8 + q];
        float4 v2 = f4[(size_t)p1.x * 8 + q];
        float4 v3 = f4[(size_t)p1.z * 8 + q];
        float n0 = __int_as_float(p0.y), n1 = __int_as_float(p0.w);
        float n2 = __int_as_float(p1.y), n3 = __int_as_float(p1.w);
        acc.x += n0 * v0.x + n1 * v1.x + n2 * v2.x + n3 * v3.x;
        acc.y += n0 * v0.y + n1 * v1.y + n2 * v2.y + n3 * v3.y;
        acc.z += n0 * v0.z + n1 * v1.z + n2 * v2.z + n3 * v3.z;
        acc.w += n0 * v0.w + n1 * v1.w + n2 * v2.w + n3 * v3.w;
    }
    for (; e < e1; ++e) {
        int2 r = erec[e];
        float nm = __int_as_float(r.y);
        float4 v = f4[(size_t)r.x * 8 + q];
        acc.x += nm * v.x; acc.y += nm * v.y; acc.z += nm * v.z; acc.w += nm * v.w;
    }
    ((float4*)out)[n * 8 + q] = acc;
}

// ---------- per-timestep ----------

static __device__ __forceinline__
void tr_body(int bid, int t, const float* __restrict__ aTt,
             const float* __restrict__ csagg, const float* __restrict__ w0,
             const float* __restrict__ b0, const float* __restrict__ w1,
             half_t* __restrict__ g1h) {
    int n = bid * 256 + threadIdx.x;
    if (n >= N_) return;
    float av = aTt[(size_t)t * N_ + n];
    float h1[GH_];
#pragma unroll
    for (int k = 0; k < GH_; ++k) {
        float v = av * w0[k] + csagg[(size_t)n * GH_ + k] + b0[k];
        h1[k] = v > 0.0f ? v : 0.0f;
    }
    half8 o[4];
#pragma unroll
    for (int j = 0; j < GH_; ++j) {
        float v = 0.0f;
#pragma unroll
        for (int k = 0; k < GH_; ++k) v += h1[k] * w1[k * GH_ + j];
        o[j >> 3][j & 7] = (half_t)v;
    }
    half8* dst = (half8*)(g1h + (size_t)n * GH_);
#pragma unroll
    for (int c = 0; c < 4; ++c) dst[c] = o[c];
}

// t=0 transform only
__global__ __launch_bounds__(256)
void k_tr0(const float* __restrict__ aTt, const float* __restrict__ csagg,
           const float* __restrict__ w0, const float* __restrict__ b0,
           const float* __restrict__ w1, half_t* __restrict__ g1h) {
    tr_body(blockIdx.x, 0, aTt, csagg, w0, b0, w1, g1h);
}

// fused: [gather(t) -> LDS -> gru(t)] on blocks [0,GRU_BLOCKS),
//        transform(t+1) into g1nxt on the rest (double-buffered g1h)
__global__ __launch_bounds__(256)
void k_step(const int* __restrict__ row_ptr, const int2* __restrict__ erec,
            const float* __restrict__ selfn, const half_t* __restrict__ g1cur,
            half_t* __restrict__ g1nxt, const float* __restrict__ b1,
            const float* __restrict__ wT, const float* __restrict__ bih,
            const float* __restrict__ bhh, float* __restrict__ hA,
            const float* __restrict__ aTt, int tnext,
            const float* __restrict__ csagg, const float* __restrict__ w0,
            const float* __restrict__ b0, const float* __restrict__ w1,
            int do_tr) {
    if ((int)blockIdx.x >= GRU_BLOCKS_) {
        if (do_tr)
            tr_body((int)blockIdx.x - GRU_BLOCKS_, tnext, aTt, csagg, w0, b0, w1, g1nxt);
        return;
    }
    __shared__ float xL[64 * XL_STRIDE_];
    int tid = threadIdx.x;
    // ---- gather phase: 4 lanes/node, 64 nodes/block ----
    {
        int nl = tid >> 2, q = tid & 3;
        int n = blockIdx.x * 64 + nl;
        if (n < N_) {
            const half8* f8 = (const half8*)g1cur;
            float acc[8];
            half8 sv = f8[(size_t)n * 4 + q];
            float sn = selfn[n];
#pragma unroll
            for (int i = 0; i < 8; ++i) acc[i] = sn * (float)sv[i];
            int e0 = row_ptr[n], e1 = row_ptr[n + 1];
            int e = e0;
            for (; e < e1 && (e & 7); ++e) {
                int2 r = erec[e];
                float nm = __int_as_float(r.y);
                half8 v = f8[(size_t)r.x * 4 + q];
#pragma unroll
                for (int i = 0; i < 8; ++i) acc[i] += nm * (float)v[i];
            }
            for (; e + 8 <= e1; e += 8) {
                int4 p0 = *(const int4*)(erec + e);
                int4 p1 = *(const int4*)(erec + e + 2);
                int4 p2 = *(const int4*)(erec + e + 4);
                int4 p3 = *(const int4*)(erec + e + 6);
                half8 v0 = f8[(size_t)p0.x * 4 + q];
                half8 v1 = f8[(size_t)p0.z * 4 + q];
                half8 v2 = f8[(size_t)p1.x * 4 + q];
                half8 v3 = f8[(size_t)p1.z * 4 + q];
                half8 v4 = f8[(size_t)p2.x * 4 + q];
                half8 v5 = f8[(size_t)p2.z * 4 + q];
                half8 v6 = f8[(size_t)p3.x * 4 + q];
                half8 v7 = f8[(size_t)p3.z * 4 + q];
                float n0 = __int_as_float(p0.y), n1 = __int_as_float(p0.w);
                float n2 = __int_as_float(p1.y), n3 = __int_as_float(p1.w);
                float n4 = __int_as_float(p2.y), n5 = __int_as_float(p2.w);
                float n6 = __int_as_float(p3.y), n7 = __int_as_float(p3.w);
#pragma unroll
                for (int i = 0; i < 8; ++i)
                    acc[i] += n0 * (float)v0[i] + n1 * (float)v1[i]
                            + n2 * (float)v2[i] + n3 * (float)v3[i]
                            + n4 * (float)v4[i] + n5 * (float)v5[i]
                            + n6 * (float)v6[i] + n7 * (float)v7[i];
            }
            for (; e < e1; ++e) {
                int2 r = erec[e];
                float nm = __int_as_float(r.y);
                half8 v = f8[(size_t)r.x * 4 + q];
#pragma unroll
                for (int i = 0; i < 8; ++i) acc[i] += nm * (float)v[i];
            }
            const float* bb = b1 + q * 8;
            float* xo = xL + nl * XL_STRIDE_ + q * 8;
#pragma unroll
            for (int i = 0; i < 8; ++i) xo[i] = fmaxf(acc[i] + bb[i], 0.0f);
        }
    }
    __syncthreads();
    // ---- gru phase: lane j owns output row j; wave handles 16 nodes ----
    int j = tid & 63;
    int wv = __builtin_amdgcn_readfirstlane(tid >> 6);
    int nb = blockIdx.x * 64 + wv * 16;
    if (nb >= N_) return;                 // after barrier: safe
    float accr[16], accz[16], accnx[16], accnh[16];
#pragma unroll
    for (int i = 0; i < 16; ++i) { accr[i] = 0; accz[i] = 0; accnx[i] = 0; accnh[i] = 0; }
    const float* xb = xL + (size_t)wv * 16 * XL_STRIDE_;
    const float* hb = hA + (size_t)nb * RH_;
#pragma unroll 4
    for (int k = 0; k < 32; ++k) {
        float wr = wT[k * 192 + j];
        float wz = wT[k * 192 + 64 + j];
        float wn = wT[k * 192 + 128 + j];
#pragma unroll
        for (int i = 0; i < 16; ++i) {
            float xv = xb[i * XL_STRIDE_ + k];   // uniform -> ds broadcast
            accr[i] += wr * xv; accz[i] += wz * xv; accnx[i] += wn * xv;
        }
    }
#pragma unroll 2
    for (int k = 0; k < 64; ++k) {
        float wr = wT[(32 + k) * 192 + j];
        float wz = wT[(32 + k) * 192 + 64 + j];
        float wn = wT[(32 + k) * 192 + 128 + j];
#pragma unroll
        for (int i = 0; i < 16; ++i) {
            float hv = hb[i * RH_ + k];          // uniform -> s_load
            accr[i] += wr * hv; accz[i] += wz * hv; accnh[i] += wn * hv;
        }
    }
    float br  = bih[j] + bhh[j];
    float bz  = bih[64 + j] + bhh[64 + j];
    float bnx = bih[128 + j];
    float bnh = bhh[128 + j];
#pragma unroll
    for (int i = 0; i < 16; ++i) {
        float h_old = hb[i * RH_ + j];
        float r = fast_sigmoid(accr[i] + br);
        float z = fast_sigmoid(accz[i] + bz);
        float c = fast_tanh(accnx[i] + bnx + r * (accnh[i] + bnh));
        hA[(size_t)(nb + i) * RH_ + j] = (1.0f - z) * c + z * h_old;
    }
}

__global__ __launch_bounds__(256)
void k_mlp(const float* __restrict__ hA, const float* __restrict__ w1,
           const float* __restrict__ b1, const float* __restrict__ w2,
           const float* __restrict__ b2, float* __restrict__ out) {
    int n = blockIdx.x * blockDim.x + threadIdx.x;
    if (n >= N_) return;
    float h[RH_];
    const float4* h4 = (const float4*)(hA + (size_t)n * RH_);
#pragma unroll
    for (int q = 0; q < 16; ++q) {
        float4 v = h4[q];
        h[q * 4 + 0] = v.x; h[q * 4 + 1] = v.y; h[q * 4 + 2] = v.z; h[q * 4 + 3] = v.w;
    }
    float acc = b2[0];
#pragma unroll 1
    for (int j = 0; j < RH_; ++j) {
        float v = b1[j];
#pragma unroll
        for (int k = 0; k < RH_; ++k) v += w1[j * RH_ + k] * h[k];
        v = v > 0.0f ? v : 0.0f;
        acc += w2[j] * v;
    }
    out[n] = acc;
}

extern "C" void kernel_launch(void* const* d_in, const int* in_sizes, int n_in,
                              void* d_out, int out_size, void* d_ws, size_t ws_size,
                              hipStream_t stream) {
    const float* dyn     = (const float*)d_in[0];
    const float* statics = (const float*)d_in[1];
    const int*   ei      = (const int*)d_in[2];
    const float* w0      = (const float*)d_in[3];
    const float* b0      = (const float*)d_in[4];
    const float* w1      = (const float*)d_in[5];
    const float* b1      = (const float*)d_in[6];
    const float* wih     = (const float*)d_in[7];
    const float* whh     = (const float*)d_in[8];
    const float* bih     = (const float*)d_in[9];
    const float* bhh     = (const float*)d_in[10];
    const float* mw1     = (const float*)d_in[11];
    const float* mb1     = (const float*)d_in[12];
    const float* mw2     = (const float*)d_in[13];
    const float* mb2     = (const float*)d_in[14];
    const int* src = ei;
    const int* dst = ei + E_;

    char* ws = (char*)d_ws;
    auto alloc = [&](size_t elems) {        // 4B units, 256B-aligned blocks
        elems = (elems + 63) & ~(size_t)63;
        void* p = ws; ws += elems * 4; return p;
    };
    int*    deg     = (int*)alloc(N_);
    int*    row_ptr = (int*)alloc(N_ + 4);
    int*    cursor  = (int*)alloc(N_);
    int2*   erec    = (int2*)alloc((size_t)E_ * 2);
    float*  dinv    = (float*)alloc(N_);
    float*  selfn   = (float*)alloc(N_);
    float*  h0s     = (float*)alloc(32 * N_);
    float*  csagg   = (float*)alloc(32 * N_);
    half_t* g1h0    = (half_t*)alloc(16 * N_);
    half_t* g1h1    = (half_t*)alloc(16 * N_);
    float*  hA      = (float*)alloc(64 * N_);
    float*  dynT    = (float*)alloc(64 * N_);
    float*  aT      = (float*)alloc(64 * N_);
    float*  aTt     = (float*)alloc(64 * N_);
    float*  wT      = (float*)alloc(96 * 192);

    auto cdiv = [](long long x, int b) { return (unsigned)((x + b - 1) / b); };
    const int B = 256;

    hipMemsetAsync(deg, 0, N_ * sizeof(int), stream);
    hipMemsetAsync(cursor, 0, N_ * sizeof(int), stream);
    hipMemsetAsync(hA, 0, (size_t)RH_ * N_ * sizeof(float), stream);

    k_transpose<<<cdiv(N_, 64), dim3(64, 4), 0, stream>>>(dyn, dynT);
    k_deg<<<cdiv(E_, B), B, 0, stream>>>(dst, deg);
    k_scan<<<1, 1024, 0, stream>>>(deg, row_ptr);
    k_node_init<<<cdiv(N_, B), B, 0, stream>>>(deg, statics, w0, dinv, selfn, h0s);
    k_scatter<<<cdiv(E_, B), B, 0, stream>>>(src, dst, dinv, row_ptr, cursor, erec);
    k_wt<<<cdiv(96 * 192, B), B, 0, stream>>>(wih, whh, wT);
    k_gather32f<<<cdiv((long long)N_ * 8, B), B, 0, stream>>>(row_ptr, erec, selfn,
                                                              h0s, csagg);
    k_aall<<<cdiv((long long)N_ * 64, B), B, 0, stream>>>(row_ptr, erec, selfn,
                                                          dynT, aT);
    k_trB<<<cdiv(N_, 64), dim3(64, 4), 0, stream>>>(aT, aTt);

    k_tr0<<<TR_BLOCKS_, B, 0, stream>>>(aTt, csagg, w0, b0, w1, g1h0);
    for (int t = 0; t < T_; ++t) {
        half_t* cur = (t & 1) ? g1h1 : g1h0;
        half_t* nxt = (t & 1) ? g1h0 : g1h1;
        int do_tr = (t + 1 < T_) ? 1 : 0;
        unsigned grid = GRU_BLOCKS_ + (do_tr ? TR_BLOCKS_ : 0);
        k_step<<<grid, B, 0, stream>>>(row_ptr, erec, selfn, cur, nxt, b1,
                                       wT, bih, bhh, hA,
                                       aTt, t + 1, csagg, w0, b0, w1, do_tr);
    }
    k_mlp<<<cdiv(N_, B), B, 0, stream>>>(hA, mw1, mb1, mw2, mb2, (float*)d_out);
}

// Round 6
// 4187.476 us; speedup vs baseline: 16.4369x; 1.3499x over previous
//
#include <hip/hip_runtime.h>
#include <hip/hip_bf16.h>

#define T_   64
#define N_   50000
#define E_   1600000
#define GH_  32
#define RH_  64
#define TB_  8                     // timesteps per gather pass
#define NP_  (T_ / TB_)            // 8 passes

typedef _Float16 half_t;
typedef __attribute__((ext_vector_type(8))) _Float16 half8;

static __device__ __forceinline__ float fast_sigmoid(float v) {
    float e = __expf(-v);
    return __builtin_amdgcn_rcpf(1.0f + e);
}
static __device__ __forceinline__ float fast_tanh(float v) {
    return 2.0f * fast_sigmoid(2.0f * v) - 1.0f;
}

// ---------- prologue ----------

// dyn [T,N] -> dynT [N,T]
__global__ __launch_bounds__(256)
void k_transpose(const float* __restrict__ dyn, float* __restrict__ dynT) {
    __shared__ float tile[64][65];
    int n0 = blockIdx.x * 64;
    int tx = threadIdx.x, ty = threadIdx.y;
#pragma unroll
    for (int r = 0; r < 16; ++r) {
        int t = r * 4 + ty;
        int n = n0 + tx;
        tile[t][tx] = (n < N_) ? dyn[(size_t)t * N_ + n] : 0.0f;
    }
    __syncthreads();
#pragma unroll
    for (int r = 0; r < 16; ++r) {
        int nl = r * 4 + ty;
        int n = n0 + nl;
        if (n < N_) dynT[(size_t)n * 64 + tx] = tile[tx][nl];
    }
}

__global__ void k_deg(const int* __restrict__ dst, int* __restrict__ deg) {
    int e = blockIdx.x * blockDim.x + threadIdx.x;
    if (e < E_) atomicAdd(&deg[dst[e]], 1);
}

// 3-phase parallel scan: per-block inclusive -> scan block sums -> add offsets
__global__ __launch_bounds__(256)
void k_scanA(const int* __restrict__ deg, int* __restrict__ row_ptr,
             int* __restrict__ bsum) {
    __shared__ int buf[256];
    int tid = threadIdx.x;
    int i = blockIdx.x * 256 + tid;
    int v = (i < N_) ? deg[i] : 0;
    buf[tid] = v;
    __syncthreads();
#pragma unroll
    for (int off = 1; off < 256; off <<= 1) {
        int t = (tid >= off) ? buf[tid - off] : 0;
        __syncthreads();
        buf[tid] += t;
        __syncthreads();
    }
    if (i < N_) row_ptr[i + 1] = buf[tid];
    if (tid == 255) bsum[blockIdx.x] = buf[255];
}
__global__ __launch_bounds__(256)
void k_scanB(int* __restrict__ bsum, int nb) {
    __shared__ int buf[256];
    int tid = threadIdx.x;
    buf[tid] = (tid < nb) ? bsum[tid] : 0;
    __syncthreads();
#pragma unroll
    for (int off = 1; off < 256; off <<= 1) {
        int t = (tid >= off) ? buf[tid - off] : 0;
        __syncthreads();
        buf[tid] += t;
        __syncthreads();
    }
    if (tid < nb) bsum[tid] = (tid > 0) ? buf[tid - 1] : 0;  // exclusive
}
__global__ __launch_bounds__(256)
void k_scanC(int* __restrict__ row_ptr, const int* __restrict__ bsum) {
    int i = blockIdx.x * 256 + threadIdx.x;
    if (i == 0) row_ptr[0] = 0;
    if (i < N_) row_ptr[i + 1] += bsum[blockIdx.x];
}

__global__ __launch_bounds__(256)
void k_node_init(const int* __restrict__ deg,
                 const float* __restrict__ statics,
                 const float* __restrict__ w0,
                 float* __restrict__ dinv,
                 float* __restrict__ selfn,
                 float* __restrict__ h0s) {
    int n = blockIdx.x * blockDim.x + threadIdx.x;
    if (n >= N_) return;
    float d  = (float)deg[n] + 1.0f;
    float di = rsqrtf(d);
    dinv[n] = di;
    selfn[n] = di * di;
    float s[6];
#pragma unroll
    for (int j = 0; j < 6; ++j) s[j] = statics[n * 6 + j];
#pragma unroll
    for (int k = 0; k < GH_; ++k) {
        float v = 0.0f;
#pragma unroll
        for (int j = 0; j < 6; ++j) v += s[j] * w0[(1 + j) * GH_ + k];
        h0s[n * GH_ + k] = v;
    }
}

// interleaved 8-byte edge record {src, norm}
__global__ void k_scatter(const int* __restrict__ src, const int* __restrict__ dst,
                          const float* __restrict__ dinv,
                          const int* __restrict__ row_ptr, int* __restrict__ cursor,
                          int2* __restrict__ erec) {
    int e = blockIdx.x * blockDim.x + threadIdx.x;
    if (e >= E_) return;
    int s = src[e], d = dst[e];
    int pos = row_ptr[d] + atomicAdd(&cursor[d], 1);
    erec[pos] = make_int2(s, __float_as_int(dinv[s] * dinv[d]));
}

__global__ void k_wt(const float* __restrict__ wih, const float* __restrict__ whh,
                     float* __restrict__ wT) {
    int idx = blockIdx.x * 256 + threadIdx.x;
    if (idx >= 96 * 192) return;
    int k = idx / 192, m = idx % 192;
    wT[idx] = (k < 32) ? wih[m * 32 + k] : whh[m * 64 + (k - 32)];
}

// aT[n][t], wave per node, lane=t
__global__ __launch_bounds__(256)
void k_aall(const int* __restrict__ row_ptr, const int2* __restrict__ erec,
            const float* __restrict__ selfn,
            const float* __restrict__ dynT, float* __restrict__ aT) {
    int gid = blockIdx.x * 256 + threadIdx.x;
    int n = gid >> 6, lane = gid & 63;
    if (n >= N_) return;
    float acc = selfn[n] * dynT[(size_t)n * 64 + lane];
    int e0 = row_ptr[n], e1 = row_ptr[n + 1];
    int e = e0;
    for (; e < e1 && (e & 3); ++e) {
        int2 r = erec[e];
        acc += __int_as_float(r.y) * dynT[(size_t)r.x * 64 + lane];
    }
    for (; e + 4 <= e1; e += 4) {
        int4 p0 = *(const int4*)(erec + e);
        int4 p1 = *(const int4*)(erec + e + 2);
        float v0 = dynT[(size_t)p0.x * 64 + lane];
        float v1 = dynT[(size_t)p0.z * 64 + lane];
        float v2 = dynT[(size_t)p1.x * 64 + lane];
        float v3 = dynT[(size_t)p1.z * 64 + lane];
        acc += __int_as_float(p0.y) * v0 + __int_as_float(p0.w) * v1
             + __int_as_float(p1.y) * v2 + __int_as_float(p1.w) * v3;
    }
    for (; e < e1; ++e) {
        int2 r = erec[e];
        acc += __int_as_float(r.y) * dynT[(size_t)r.x * 64 + lane];
    }
    aT[(size_t)n * 64 + lane] = acc;
}

// fp32 gather (one-time, csagg): 8 lanes/node, float4
__global__ __launch_bounds__(256)
void k_gather32f(const int* __restrict__ row_ptr, const int2* __restrict__ erec,
                 const float* __restrict__ selfn,
                 const float* __restrict__ feat, float* __restrict__ out) {
    int gid = blockIdx.x * 256 + threadIdx.x;
    int n = gid >> 3, q = gid & 7;
    if (n >= N_) return;
    const float4* f4 = (const float4*)feat;
    float4 acc = f4[n * 8 + q];
    float sn = selfn[n];
    acc.x *= sn; acc.y *= sn; acc.z *= sn; acc.w *= sn;
    int e0 = row_ptr[n], e1 = row_ptr[n + 1];
    int e = e0;
    for (; e < e1 && (e & 3); ++e) {
        int2 r = erec[e];
        float nm = __int_as_float(r.y);
        float4 v = f4[(size_t)r.x * 8 + q];
        acc.x += nm * v.x; acc.y += nm * v.y; acc.z += nm * v.z; acc.w += nm * v.w;
    }
    for (; e + 4 <= e1; e += 4) {
        int4 p0 = *(const int4*)(erec + e);
        int4 p1 = *(const int4*)(erec + e + 2);
        float4 v0 = f4[(size_t)p0.x * 8 + q];
        float4 v1 = f4[(size_t)p0.z * 8 + q];
        float4 v2 = f4[(size_t)p1.x * 8 + q];
        float4 v3 = f4[(size_t)p1.z * 8 + q];
        float n0 = __int_as_float(p0.y), n1 = __int_as_float(p0.w);
        float n2 = __int_as_float(p1.y), n3 = __int_as_float(p1.w);
        acc.x += n0 * v0.x + n1 * v1.x + n2 * v2.x + n3 * v3.x;
        acc.y += n0 * v0.y + n1 * v1.y + n2 * v2.y + n3 * v3.y;
        acc.z += n0 * v0.z + n1 * v1.z + n2 * v2.z + n3 * v3.z;
        acc.w += n0 * v0.w + n1 * v1.w + n2 * v2.w + n3 * v3.w;
    }
    for (; e < e1; ++e) {
        int2 r = erec[e];
        float nm = __int_as_float(r.y);
        float4 v = f4[(size_t)r.x * 8 + q];
        acc.x += nm * v.x; acc.y += nm * v.y; acc.z += nm * v.z; acc.w += nm * v.w;
    }
    ((float4*)out)[n * 8 + q] = acc;
}

// ---------- per-pass (Tb=8 timesteps) ----------

// g1blk[n][u][32] fp16 for u = 0..7 (t = tb+u). Pure feed-forward from aT.
__global__ __launch_bounds__(256)
void k_g1blk(const float* __restrict__ aT, const float* __restrict__ csagg,
             const float* __restrict__ w0, const float* __restrict__ b0,
             const float* __restrict__ w1, half_t* __restrict__ g1blk, int tb) {
    int n = blockIdx.x * 256 + threadIdx.x;
    if (n >= N_) return;
    float c[GH_];
#pragma unroll
    for (int k = 0; k < GH_; ++k) c[k] = csagg[(size_t)n * GH_ + k] + b0[k];
    const float* at = aT + (size_t)n * 64 + tb;
    half8* outp = (half8*)(g1blk + (size_t)n * (TB_ * GH_));
#pragma unroll 1
    for (int u = 0; u < TB_; ++u) {
        float av = at[u];
        float h1[GH_];
#pragma unroll
        for (int k = 0; k < GH_; ++k) {
            float v = av * w0[k] + c[k];
            h1[k] = v > 0.0f ? v : 0.0f;
        }
        half8 o[4];
#pragma unroll
        for (int j = 0; j < GH_; ++j) {
            float v = 0.0f;
#pragma unroll
            for (int k = 0; k < GH_; ++k) v += h1[k] * w1[k * GH_ + j];
            o[j >> 3][j & 7] = (half_t)v;
        }
#pragma unroll
        for (int cc = 0; cc < 4; ++cc) outp[u * 4 + cc] = o[cc];
    }
}

// gather all 8 timesteps in one pass: 8 lanes/node; per edge, contiguous 512B.
// lane q handles chunks q+8u (16B each): t = (q>>2)+2u, k0 = (q&3)*8.
// epilogue: xblk[u][n][k] = relu(agg + b1)  (fp32)
__global__ __launch_bounds__(256)
void k_gatherx(const int* __restrict__ row_ptr, const int2* __restrict__ erec,
               const float* __restrict__ selfn, const half_t* __restrict__ g1blk,
               const float* __restrict__ b1, float* __restrict__ xblk) {
    int gid = blockIdx.x * 256 + threadIdx.x;
    int n = gid >> 3, q = gid & 7;
    if (n >= N_) return;
    const half8* g8 = (const half8*)g1blk;   // node row = 32 chunks of 16B
    float acc[4][8];
    {
        float sn = selfn[n];
#pragma unroll
        for (int u = 0; u < 4; ++u) {
            half8 sv = g8[(size_t)n * 32 + q + 8 * u];
#pragma unroll
            for (int i = 0; i < 8; ++i) acc[u][i] = sn * (float)sv[i];
        }
    }
    int e0 = row_ptr[n], e1 = row_ptr[n + 1];
    int e = e0;
    for (; e < e1 && (e & 3); ++e) {
        int2 r = erec[e];
        float nm = __int_as_float(r.y);
        size_t base = (size_t)r.x * 32 + q;
#pragma unroll
        for (int u = 0; u < 4; ++u) {
            half8 v = g8[base + 8 * u];
#pragma unroll
            for (int i = 0; i < 8; ++i) acc[u][i] += nm * (float)v[i];
        }
    }
    for (; e + 4 <= e1; e += 4) {
        int4 p0 = *(const int4*)(erec + e);
        int4 p1 = *(const int4*)(erec + e + 2);
        size_t b0a = (size_t)p0.x * 32 + q;
        size_t b1a = (size_t)p0.z * 32 + q;
        size_t b2a = (size_t)p1.x * 32 + q;
        size_t b3a = (size_t)p1.z * 32 + q;
        float n0 = __int_as_float(p0.y), n1 = __int_as_float(p0.w);
        float n2 = __int_as_float(p1.y), n3 = __int_as_float(p1.w);
        half8 v0[4], v1[4], v2[4], v3[4];
#pragma unroll
        for (int u = 0; u < 4; ++u) {
            v0[u] = g8[b0a + 8 * u];
            v1[u] = g8[b1a + 8 * u];
            v2[u] = g8[b2a + 8 * u];
            v3[u] = g8[b3a + 8 * u];
        }
#pragma unroll
        for (int u = 0; u < 4; ++u)
#pragma unroll
            for (int i = 0; i < 8; ++i)
                acc[u][i] += n0 * (float)v0[u][i] + n1 * (float)v1[u][i]
                           + n2 * (float)v2[u][i] + n3 * (float)v3[u][i];
    }
    for (; e < e1; ++e) {
        int2 r = erec[e];
        float nm = __int_as_float(r.y);
        size_t base = (size_t)r.x * 32 + q;
#pragma unroll
        for (int u = 0; u < 4; ++u) {
            half8 v = g8[base + 8 * u];
#pragma unroll
            for (int i = 0; i < 8; ++i) acc[u][i] += nm * (float)v[i];
        }
    }
    int kc = (q & 3) * 8;
    const float* bb = b1 + kc;
#pragma unroll
    for (int u = 0; u < 4; ++u) {
        int t = (q >> 2) + 2 * u;
        float4 o0, o1;
        o0.x = fmaxf(acc[u][0] + bb[0], 0.0f);
        o0.y = fmaxf(acc[u][1] + bb[1], 0.0f);
        o0.z = fmaxf(acc[u][2] + bb[2], 0.0f);
        o0.w = fmaxf(acc[u][3] + bb[3], 0.0f);
        o1.x = fmaxf(acc[u][4] + bb[4], 0.0f);
        o1.y = fmaxf(acc[u][5] + bb[5], 0.0f);
        o1.z = fmaxf(acc[u][6] + bb[6], 0.0f);
        o1.w = fmaxf(acc[u][7] + bb[7], 0.0f);
        float4* out = (float4*)(xblk + ((size_t)t * N_ + n) * GH_ + kc);
        out[0] = o0; out[1] = o1;
    }
}

// GRU: lane j owns gate row j; wave handles 16 nodes; x/h via uniform s_loads.
__global__ __launch_bounds__(256)
void k_gru(const float* __restrict__ xA,    // [N,32] slice, relu already applied
           const float* __restrict__ wT,    // [96][192]
           const float* __restrict__ bih, const float* __restrict__ bhh,
           float* __restrict__ hA) {        // [N,64]
    int j = threadIdx.x & 63;
    int wv = __builtin_amdgcn_readfirstlane(threadIdx.x >> 6);
    int nb = blockIdx.x * 64 + wv * 16;
    if (nb >= N_) return;
    float accr[16], accz[16], accnx[16], accnh[16];
#pragma unroll
    for (int i = 0; i < 16; ++i) { accr[i] = 0; accz[i] = 0; accnx[i] = 0; accnh[i] = 0; }
    const float* xb = xA + (size_t)nb * GH_;
    const float* hb = hA + (size_t)nb * RH_;
#pragma unroll 4
    for (int k = 0; k < 32; ++k) {
        float wr = wT[k * 192 + j];
        float wz = wT[k * 192 + 64 + j];
        float wn = wT[k * 192 + 128 + j];
#pragma unroll
        for (int i = 0; i < 16; ++i) {
            float xv = xb[i * GH_ + k];
            accr[i] += wr * xv; accz[i] += wz * xv; accnx[i] += wn * xv;
        }
    }
#pragma unroll 2
    for (int k = 0; k < 64; ++k) {
        float wr = wT[(32 + k) * 192 + j];
        float wz = wT[(32 + k) * 192 + 64 + j];
        float wn = wT[(32 + k) * 192 + 128 + j];
#pragma unroll
        for (int i = 0; i < 16; ++i) {
            float hv = hb[i * RH_ + k];
            accr[i] += wr * hv; accz[i] += wz * hv; accnh[i] += wn * hv;
        }
    }
    float br  = bih[j] + bhh[j];
    float bz  = bih[64 + j] + bhh[64 + j];
    float bnx = bih[128 + j];
    float bnh = bhh[128 + j];
#pragma unroll
    for (int i = 0; i < 16; ++i) {
        float h_old = hb[i * RH_ + j];
        float r = fast_sigmoid(accr[i] + br);
        float z = fast_sigmoid(accz[i] + bz);
        float c = fast_tanh(accnx[i] + bnx + r * (accnh[i] + bnh));
        hA[(size_t)(nb + i) * RH_ + j] = (1.0f - z) * c + z * h_old;
    }
}

__global__ __launch_bounds__(256)
void k_mlp(const float* __restrict__ hA, const float* __restrict__ w1,
           const float* __restrict__ b1, const float* __restrict__ w2,
           const float* __restrict__ b2, float* __restrict__ out) {
    int n = blockIdx.x * blockDim.x + threadIdx.x;
    if (n >= N_) return;
    float h[RH_];
    const float4* h4 = (const float4*)(hA + (size_t)n * RH_);
#pragma unroll
    for (int q = 0; q < 16; ++q) {
        float4 v = h4[q];
        h[q * 4 + 0] = v.x; h[q * 4 + 1] = v.y; h[q * 4 + 2] = v.z; h[q * 4 + 3] = v.w;
    }
    float acc = b2[0];
#pragma unroll 1
    for (int j = 0; j < RH_; ++j) {
        float v = b1[j];
#pragma unroll
        for (int k = 0; k < RH_; ++k) v += w1[j * RH_ + k] * h[k];
        v = v > 0.0f ? v : 0.0f;
        acc += w2[j] * v;
    }
    out[n] = acc;
}

extern "C" void kernel_launch(void* const* d_in, const int* in_sizes, int n_in,
                              void* d_out, int out_size, void* d_ws, size_t ws_size,
                              hipStream_t stream) {
    const float* dyn     = (const float*)d_in[0];
    const float* statics = (const float*)d_in[1];
    const int*   ei      = (const int*)d_in[2];
    const float* w0      = (const float*)d_in[3];
    const float* b0      = (const float*)d_in[4];
    const float* w1      = (const float*)d_in[5];
    const float* b1      = (const float*)d_in[6];
    const float* wih     = (const float*)d_in[7];
    const float* whh     = (const float*)d_in[8];
    const float* bih     = (const float*)d_in[9];
    const float* bhh     = (const float*)d_in[10];
    const float* mw1     = (const float*)d_in[11];
    const float* mb1     = (const float*)d_in[12];
    const float* mw2     = (const float*)d_in[13];
    const float* mb2     = (const float*)d_in[14];
    const int* src = ei;
    const int* dst = ei + E_;

    char* ws = (char*)d_ws;
    auto alloc = [&](size_t elems) {        // 4B units, 256B-aligned blocks
        elems = (elems + 63) & ~(size_t)63;
        void* p = ws; ws += elems * 4; return p;
    };
    int*    deg     = (int*)alloc(N_);
    int*    row_ptr = (int*)alloc(N_ + 4);
    int*    bsum    = (int*)alloc(256);
    int*    cursor  = (int*)alloc(N_);
    int2*   erec    = (int2*)alloc((size_t)E_ * 2);
    float*  dinv    = (float*)alloc(N_);
    float*  selfn   = (float*)alloc(N_);
    float*  h0s     = (float*)alloc(32 * N_);
    float*  csagg   = (float*)alloc(32 * N_);
    half_t* g1blk   = (half_t*)alloc((size_t)N_ * TB_ * GH_ / 2);  // fp16 [N][8][32]
    float*  xblk    = (float*)alloc((size_t)TB_ * N_ * GH_);       // fp32 [8][N][32]
    float*  hA      = (float*)alloc(64 * N_);
    float*  dynT    = (float*)alloc(64 * N_);
    float*  aT      = (float*)alloc(64 * N_);
    float*  wT      = (float*)alloc(96 * 192);

    auto cdiv = [](long long x, int b) { return (unsigned)((x + b - 1) / b); };
    const int B = 256;
    const unsigned NB = cdiv(N_, B);       // 196

    hipMemsetAsync(deg, 0, N_ * sizeof(int), stream);
    hipMemsetAsync(cursor, 0, N_ * sizeof(int), stream);
    hipMemsetAsync(hA, 0, (size_t)RH_ * N_ * sizeof(float), stream);

    k_transpose<<<cdiv(N_, 64), dim3(64, 4), 0, stream>>>(dyn, dynT);
    k_deg<<<cdiv(E_, B), B, 0, stream>>>(dst, deg);
    k_scanA<<<NB, B, 0, stream>>>(deg, row_ptr, bsum);
    k_scanB<<<1, B, 0, stream>>>(bsum, (int)NB);
    k_scanC<<<NB, B, 0, stream>>>(row_ptr, bsum);
    k_node_init<<<NB, B, 0, stream>>>(deg, statics, w0, dinv, selfn, h0s);
    k_scatter<<<cdiv(E_, B), B, 0, stream>>>(src, dst, dinv, row_ptr, cursor, erec);
    k_wt<<<cdiv(96 * 192, B), B, 0, stream>>>(wih, whh, wT);
    k_gather32f<<<cdiv((long long)N_ * 8, B), B, 0, stream>>>(row_ptr, erec, selfn,
                                                              h0s, csagg);
    k_aall<<<cdiv((long long)N_ * 64, B), B, 0, stream>>>(row_ptr, erec, selfn,
                                                          dynT, aT);

    for (int p = 0; p < NP_; ++p) {
        k_g1blk<<<NB, B, 0, stream>>>(aT, csagg, w0, b0, w1, g1blk, p * TB_);
        k_gatherx<<<cdiv((long long)N_ * 8, B), B, 0, stream>>>(row_ptr, erec, selfn,
                                                                g1blk, b1, xblk);
        for (int u = 0; u < TB_; ++u) {
            k_gru<<<cdiv(N_, 64), B, 0, stream>>>(xblk + (size_t)u * N_ * GH_,
                                                  wT, bih, bhh, hA);
        }
    }
    k_mlp<<<NB, B, 0, stream>>>(hA, mw1, mb1, mw2, mb2, (float*)d_out);
}

// Round 7
// 2069.569 us; speedup vs baseline: 33.2577x; 2.0234x over previous
//
#include <hip/hip_runtime.h>
#include <hip/hip_bf16.h>

#define T_   64
#define N_   50000
#define E_   1600000
#define GH_  32
#define RH_  64
#define TB_  8                     // timesteps per pass
#define NP_  (T_ / TB_)            // 8 passes

typedef _Float16 half_t;
typedef __attribute__((ext_vector_type(8))) _Float16 half8;
typedef __attribute__((ext_vector_type(4))) float f32x4;

static __device__ __forceinline__ float fast_sigmoid(float v) {
    float e = __expf(-v);
    return __builtin_amdgcn_rcpf(1.0f + e);
}
static __device__ __forceinline__ float fast_tanh(float v) {
    return 2.0f * fast_sigmoid(2.0f * v) - 1.0f;
}

// ---------- prologue ----------

// dyn [T,N] -> dynT [N,T]
__global__ __launch_bounds__(256)
void k_transpose(const float* __restrict__ dyn, float* __restrict__ dynT) {
    __shared__ float tile[64][65];
    int n0 = blockIdx.x * 64;
    int tx = threadIdx.x, ty = threadIdx.y;
#pragma unroll
    for (int r = 0; r < 16; ++r) {
        int t = r * 4 + ty;
        int n = n0 + tx;
        tile[t][tx] = (n < N_) ? dyn[(size_t)t * N_ + n] : 0.0f;
    }
    __syncthreads();
#pragma unroll
    for (int r = 0; r < 16; ++r) {
        int nl = r * 4 + ty;
        int n = n0 + nl;
        if (n < N_) dynT[(size_t)n * 64 + tx] = tile[tx][nl];
    }
}

__global__ void k_deg(const int* __restrict__ dst, int* __restrict__ deg) {
    int e = blockIdx.x * blockDim.x + threadIdx.x;
    if (e < E_) atomicAdd(&deg[dst[e]], 1);
}

// 3-phase parallel scan
__global__ __launch_bounds__(256)
void k_scanA(const int* __restrict__ deg, int* __restrict__ row_ptr,
             int* __restrict__ bsum) {
    __shared__ int buf[256];
    int tid = threadIdx.x;
    int i = blockIdx.x * 256 + tid;
    int v = (i < N_) ? deg[i] : 0;
    buf[tid] = v;
    __syncthreads();
#pragma unroll
    for (int off = 1; off < 256; off <<= 1) {
        int t = (tid >= off) ? buf[tid - off] : 0;
        __syncthreads();
        buf[tid] += t;
        __syncthreads();
    }
    if (i < N_) row_ptr[i + 1] = buf[tid];
    if (tid == 255) bsum[blockIdx.x] = buf[255];
}
__global__ __launch_bounds__(256)
void k_scanB(int* __restrict__ bsum, int nb) {
    __shared__ int buf[256];
    int tid = threadIdx.x;
    buf[tid] = (tid < nb) ? bsum[tid] : 0;
    __syncthreads();
#pragma unroll
    for (int off = 1; off < 256; off <<= 1) {
        int t = (tid >= off) ? buf[tid - off] : 0;
        __syncthreads();
        buf[tid] += t;
        __syncthreads();
    }
    if (tid < nb) bsum[tid] = (tid > 0) ? buf[tid - 1] : 0;
}
__global__ __launch_bounds__(256)
void k_scanC(int* __restrict__ row_ptr, const int* __restrict__ bsum) {
    int i = blockIdx.x * 256 + threadIdx.x;
    if (i == 0) row_ptr[0] = 0;
    if (i < N_) row_ptr[i + 1] += bsum[blockIdx.x];
}

__global__ __launch_bounds__(256)
void k_node_init(const int* __restrict__ deg,
                 const float* __restrict__ statics,
                 const float* __restrict__ w0,
                 float* __restrict__ dinv,
                 float* __restrict__ selfn,
                 float* __restrict__ h0s) {
    int n = blockIdx.x * blockDim.x + threadIdx.x;
    if (n >= N_) return;
    float d  = (float)deg[n] + 1.0f;
    float di = rsqrtf(d);
    dinv[n] = di;
    selfn[n] = di * di;
    float s[6];
#pragma unroll
    for (int j = 0; j < 6; ++j) s[j] = statics[n * 6 + j];
#pragma unroll
    for (int k = 0; k < GH_; ++k) {
        float v = 0.0f;
#pragma unroll
        for (int j = 0; j < 6; ++j) v += s[j] * w0[(1 + j) * GH_ + k];
        h0s[n * GH_ + k] = v;
    }
}

// interleaved 8-byte edge record {src, norm}
__global__ void k_scatter(const int* __restrict__ src, const int* __restrict__ dst,
                          const float* __restrict__ dinv,
                          const int* __restrict__ row_ptr, int* __restrict__ cursor,
                          int2* __restrict__ erec) {
    int e = blockIdx.x * blockDim.x + threadIdx.x;
    if (e >= E_) return;
    int s = src[e], d = dst[e];
    int pos = row_ptr[d] + atomicAdd(&cursor[d], 1);
    erec[pos] = make_int2(s, __float_as_int(dinv[s] * dinv[d]));
}

// combined GRU weight matrix, transposed, f16: wTh[k][m], k<32 -> wih, else whh
__global__ void k_wt(const float* __restrict__ wih, const float* __restrict__ whh,
                     half_t* __restrict__ wTh) {
    int idx = blockIdx.x * 256 + threadIdx.x;
    if (idx >= 96 * 192) return;
    int k = idx / 192, m = idx % 192;
    float v = (k < 32) ? wih[m * 32 + k] : whh[m * 64 + (k - 32)];
    wTh[idx] = (half_t)v;
}

// aT[n][t], wave per node, lane=t
__global__ __launch_bounds__(256)
void k_aall(const int* __restrict__ row_ptr, const int2* __restrict__ erec,
            const float* __restrict__ selfn,
            const float* __restrict__ dynT, float* __restrict__ aT) {
    int gid = blockIdx.x * 256 + threadIdx.x;
    int n = gid >> 6, lane = gid & 63;
    if (n >= N_) return;
    float acc = selfn[n] * dynT[(size_t)n * 64 + lane];
    int e0 = row_ptr[n], e1 = row_ptr[n + 1];
    int e = e0;
    for (; e < e1 && (e & 3); ++e) {
        int2 r = erec[e];
        acc += __int_as_float(r.y) * dynT[(size_t)r.x * 64 + lane];
    }
    for (; e + 4 <= e1; e += 4) {
        int4 p0 = *(const int4*)(erec + e);
        int4 p1 = *(const int4*)(erec + e + 2);
        float v0 = dynT[(size_t)p0.x * 64 + lane];
        float v1 = dynT[(size_t)p0.z * 64 + lane];
        float v2 = dynT[(size_t)p1.x * 64 + lane];
        float v3 = dynT[(size_t)p1.z * 64 + lane];
        acc += __int_as_float(p0.y) * v0 + __int_as_float(p0.w) * v1
             + __int_as_float(p1.y) * v2 + __int_as_float(p1.w) * v3;
    }
    for (; e < e1; ++e) {
        int2 r = erec[e];
        acc += __int_as_float(r.y) * dynT[(size_t)r.x * 64 + lane];
    }
    aT[(size_t)n * 64 + lane] = acc;
}

// fp32 gather (one-time, csagg): 8 lanes/node, float4
__global__ __launch_bounds__(256)
void k_gather32f(const int* __restrict__ row_ptr, const int2* __restrict__ erec,
                 const float* __restrict__ selfn,
                 const float* __restrict__ feat, float* __restrict__ out) {
    int gid = blockIdx.x * 256 + threadIdx.x;
    int n = gid >> 3, q = gid & 7;
    if (n >= N_) return;
    const float4* f4 = (const float4*)feat;
    float4 acc = f4[n * 8 + q];
    float sn = selfn[n];
    acc.x *= sn; acc.y *= sn; acc.z *= sn; acc.w *= sn;
    int e0 = row_ptr[n], e1 = row_ptr[n + 1];
    int e = e0;
    for (; e < e1 && (e & 3); ++e) {
        int2 r = erec[e];
        float nm = __int_as_float(r.y);
        float4 v = f4[(size_t)r.x * 8 + q];
        acc.x += nm * v.x; acc.y += nm * v.y; acc.z += nm * v.z; acc.w += nm * v.w;
    }
    for (; e + 4 <= e1; e += 4) {
        int4 p0 = *(const int4*)(erec + e);
        int4 p1 = *(const int4*)(erec + e + 2);
        float4 v0 = f4[(size_t)p0.x * 8 + q];
        float4 v1 = f4[(size_t)p0.z * 8 + q];
        float4 v2 = f4[(size_t)p1.x * 8 + q];
        float4 v3 = f4[(size_t)p1.z * 8 + q];
        float n0 = __int_as_float(p0.y), n1 = __int_as_float(p0.w);
        float n2 = __int_as_float(p1.y), n3 = __int_as_float(p1.w);
        acc.x += n0 * v0.x + n1 * v1.x + n2 * v2.x + n3 * v3.x;
        acc.y += n0 * v0.y + n1 * v1.y + n2 * v2.y + n3 * v3.y;
        acc.z += n0 * v0.z + n1 * v1.z + n2 * v2.z + n3 * v3.z;
        acc.w += n0 * v0.w + n1 * v1.w + n2 * v2.w + n3 * v3.w;
    }
    for (; e < e1; ++e) {
        int2 r = erec[e];
        float nm = __int_as_float(r.y);
        float4 v = f4[(size_t)r.x * 8 + q];
        acc.x += nm * v.x; acc.y += nm * v.y; acc.z += nm * v.z; acc.w += nm * v.w;
    }
    ((float4*)out)[n * 8 + q] = acc;
}

// ---------- per-pass (Tb=8 timesteps) ----------

// g1blk[n][u][32] fp16 for u = 0..7 (t = tb+u)
__global__ __launch_bounds__(256)
void k_g1blk(const float* __restrict__ aT, const float* __restrict__ csagg,
             const float* __restrict__ w0, const float* __restrict__ b0,
             const float* __restrict__ w1, half_t* __restrict__ g1blk, int tb) {
    int n = blockIdx.x * 256 + threadIdx.x;
    if (n >= N_) return;
    float c[GH_];
#pragma unroll
    for (int k = 0; k < GH_; ++k) c[k] = csagg[(size_t)n * GH_ + k] + b0[k];
    const float* at = aT + (size_t)n * 64 + tb;
    half8* outp = (half8*)(g1blk + (size_t)n * (TB_ * GH_));
#pragma unroll 1
    for (int u = 0; u < TB_; ++u) {
        float av = at[u];
        float h1[GH_];
#pragma unroll
        for (int k = 0; k < GH_; ++k) {
            float v = av * w0[k] + c[k];
            h1[k] = v > 0.0f ? v : 0.0f;
        }
        half8 o[4];
#pragma unroll
        for (int j = 0; j < GH_; ++j) {
            float v = 0.0f;
#pragma unroll
            for (int k = 0; k < GH_; ++k) v += h1[k] * w1[k * GH_ + j];
            o[j >> 3][j & 7] = (half_t)v;
        }
#pragma unroll
        for (int cc = 0; cc < 4; ++cc) outp[u * 4 + cc] = o[cc];
    }
}

// gather all 8 timesteps in one pass; 8 lanes/node; 512B contiguous per edge.
// epilogue: xblk[u][n][k] = relu(agg + b1)  (fp16)
__global__ __launch_bounds__(256)
void k_gatherx(const int* __restrict__ row_ptr, const int2* __restrict__ erec,
               const float* __restrict__ selfn, const half_t* __restrict__ g1blk,
               const float* __restrict__ b1, half_t* __restrict__ xblk) {
    int gid = blockIdx.x * 256 + threadIdx.x;
    int n = gid >> 3, q = gid & 7;
    if (n >= N_) return;
    const half8* g8 = (const half8*)g1blk;
    float acc[4][8];
    {
        float sn = selfn[n];
#pragma unroll
        for (int u = 0; u < 4; ++u) {
            half8 sv = g8[(size_t)n * 32 + q + 8 * u];
#pragma unroll
            for (int i = 0; i < 8; ++i) acc[u][i] = sn * (float)sv[i];
        }
    }
    int e0 = row_ptr[n], e1 = row_ptr[n + 1];
    int e = e0;
    for (; e < e1 && (e & 3); ++e) {
        int2 r = erec[e];
        float nm = __int_as_float(r.y);
        size_t base = (size_t)r.x * 32 + q;
#pragma unroll
        for (int u = 0; u < 4; ++u) {
            half8 v = g8[base + 8 * u];
#pragma unroll
            for (int i = 0; i < 8; ++i) acc[u][i] += nm * (float)v[i];
        }
    }
    for (; e + 4 <= e1; e += 4) {
        int4 p0 = *(const int4*)(erec + e);
        int4 p1 = *(const int4*)(erec + e + 2);
        size_t b0a = (size_t)p0.x * 32 + q;
        size_t b1a = (size_t)p0.z * 32 + q;
        size_t b2a = (size_t)p1.x * 32 + q;
        size_t b3a = (size_t)p1.z * 32 + q;
        float n0 = __int_as_float(p0.y), n1 = __int_as_float(p0.w);
        float n2 = __int_as_float(p1.y), n3 = __int_as_float(p1.w);
        half8 v0[4], v1[4], v2[4], v3[4];
#pragma unroll
        for (int u = 0; u < 4; ++u) {
            v0[u] = g8[b0a + 8 * u];
            v1[u] = g8[b1a + 8 * u];
            v2[u] = g8[b2a + 8 * u];
            v3[u] = g8[b3a + 8 * u];
        }
#pragma unroll
        for (int u = 0; u < 4; ++u)
#pragma unroll
            for (int i = 0; i < 8; ++i)
                acc[u][i] += n0 * (float)v0[u][i] + n1 * (float)v1[u][i]
                           + n2 * (float)v2[u][i] + n3 * (float)v3[u][i];
    }
    for (; e < e1; ++e) {
        int2 r = erec[e];
        float nm = __int_as_float(r.y);
        size_t base = (size_t)r.x * 32 + q;
#pragma unroll
        for (int u = 0; u < 4; ++u) {
            half8 v = g8[base + 8 * u];
#pragma unroll
            for (int i = 0; i < 8; ++i) acc[u][i] += nm * (float)v[i];
        }
    }
    int kc = (q & 3) * 8;
    const float* bb = b1 + kc;
#pragma unroll
    for (int u = 0; u < 4; ++u) {
        int t = (q >> 2) + 2 * u;
        half8 o;
#pragma unroll
        for (int i = 0; i < 8; ++i)
            o[i] = (half_t)fmaxf(acc[u][i] + bb[i], 0.0f);
        *(half8*)(xblk + ((size_t)t * N_ + n) * GH_ + kc) = o;
    }
}

// ---------- MFMA GRU: 8 timesteps fused, h in LDS f16 ----------
// Block: 256 thr (4 waves), 64 nodes. Wave w: nodes nb0 + w*16 .. +16.
// Per t per wave: 36 x v_mfma_f32_16x16x32_f16 (12 n-tiles x 3 k-chunks).
// A-frag: A[m=lane&15][k=quad*8+j]; B-frag: B[k=quad*8+j][n=lane&15];
// C: col=lane&15, row=quad*4+reg (all measured layouts).
#define HSTR_ 72   // hL row stride in f16: 144B = 16B-aligned, 2-way banks (free)
__global__ __launch_bounds__(256, 2)
void k_gruMM(const half_t* __restrict__ xblk,   // [TB][N][32] f16
             const half_t* __restrict__ wTh,    // [96][192] f16
             const float* __restrict__ bih, const float* __restrict__ bhh,
             half_t* __restrict__ hA) {         // [Npad][64] f16
    __shared__ half_t wL[96 * 192];
    __shared__ half_t hL[64 * HSTR_];
    int tid = threadIdx.x;
    int nb0 = blockIdx.x * 64;
    // stage weights (36 KB) coalesced
    {
        const half8* s = (const half8*)wTh;
        half8* d = (half8*)wL;
        for (int i = tid; i < 96 * 192 / 8; i += 256) d[i] = s[i];
    }
    // stage h (64 nodes x 64 f16)
    for (int i = tid; i < 64 * 8; i += 256) {
        int node = i >> 3, ch = i & 7;
        half8 v = *(const half8*)(hA + (size_t)(nb0 + node) * RH_ + ch * 8);
        *(half8*)(hL + node * HSTR_ + ch * 8) = v;
    }
    __syncthreads();
    int lane = tid & 63;
    int wv = tid >> 6;
    int c16 = lane & 15, q = lane >> 4;
    // B fragments -> VGPRs (once)
    half8 bfr[3][12];
#pragma unroll
    for (int c = 0; c < 3; ++c)
#pragma unroll
        for (int nt = 0; nt < 12; ++nt) {
#pragma unroll
            for (int j = 0; j < 8; ++j)
                bfr[c][nt][j] = wL[(c * 32 + q * 8 + j) * 192 + nt * 16 + c16];
        }
    // per-lane biases (j = jt*16 + c16)
    float br[4], bz[4], bnx[4], bnh[4];
#pragma unroll
    for (int jt = 0; jt < 4; ++jt) {
        int j = jt * 16 + c16;
        br[jt]  = bih[j] + bhh[j];
        bz[jt]  = bih[64 + j] + bhh[64 + j];
        bnx[jt] = bih[128 + j];
        bnh[jt] = bhh[128 + j];
    }
    int mrow = wv * 16 + c16;                 // node_local for A-frags
    const half_t* hrow = hL + mrow * HSTR_;
    const f32x4 zero = {0.0f, 0.0f, 0.0f, 0.0f};
#pragma unroll 1
    for (int u = 0; u < TB_; ++u) {
        half8 ax  = *(const half8*)(xblk + ((size_t)u * N_ + nb0 + mrow) * GH_ + q * 8);
        half8 ah0 = *(const half8*)(hrow + q * 8);
        half8 ah1 = *(const half8*)(hrow + 32 + q * 8);
        f32x4 Crz[8], Cnx[4], Cnh[4];
#pragma unroll
        for (int nt = 0; nt < 8; ++nt) {
            Crz[nt] = __builtin_amdgcn_mfma_f32_16x16x32_f16(ax,  bfr[0][nt], zero,     0, 0, 0);
            Crz[nt] = __builtin_amdgcn_mfma_f32_16x16x32_f16(ah0, bfr[1][nt], Crz[nt], 0, 0, 0);
            Crz[nt] = __builtin_amdgcn_mfma_f32_16x16x32_f16(ah1, bfr[2][nt], Crz[nt], 0, 0, 0);
        }
#pragma unroll
        for (int nt = 0; nt < 4; ++nt) {
            Cnx[nt] = __builtin_amdgcn_mfma_f32_16x16x32_f16(ax,  bfr[0][8 + nt], zero,     0, 0, 0);
            Cnh[nt] = __builtin_amdgcn_mfma_f32_16x16x32_f16(ah0, bfr[1][8 + nt], zero,     0, 0, 0);
            Cnh[nt] = __builtin_amdgcn_mfma_f32_16x16x32_f16(ah1, bfr[2][8 + nt], Cnh[nt], 0, 0, 0);
        }
        // epilogue: gate math; same lane holds r,z,nx,nh for (node,j)
#pragma unroll
        for (int jt = 0; jt < 4; ++jt) {
#pragma unroll
            for (int reg = 0; reg < 4; ++reg) {
                int nl = wv * 16 + q * 4 + reg;
                int jj = jt * 16 + c16;
                float hold = (float)hL[nl * HSTR_ + jj];
                float r  = fast_sigmoid(Crz[jt][reg] + br[jt]);
                float z  = fast_sigmoid(Crz[4 + jt][reg] + bz[jt]);
                float cd = fast_tanh(Cnx[jt][reg] + bnx[jt] + r * (Cnh[jt][reg] + bnh[jt]));
                hL[nl * HSTR_ + jj] = (half_t)((1.0f - z) * cd + z * hold);
            }
        }
        // wave-private nodes: DS ops in-order within wave, no barrier needed
    }
    __syncthreads();
    for (int i = tid; i < 64 * 8; i += 256) {
        int node = i >> 3, ch = i & 7;
        half8 v = *(const half8*)(hL + node * HSTR_ + ch * 8);
        *(half8*)(hA + (size_t)(nb0 + node) * RH_ + ch * 8) = v;
    }
}

__global__ __launch_bounds__(256)
void k_mlp(const half_t* __restrict__ hA, const float* __restrict__ w1,
           const float* __restrict__ b1, const float* __restrict__ w2,
           const float* __restrict__ b2, float* __restrict__ out) {
    int n = blockIdx.x * blockDim.x + threadIdx.x;
    if (n >= N_) return;
    float h[RH_];
    const half8* h8 = (const half8*)(hA + (size_t)n * RH_);
#pragma unroll
    for (int c = 0; c < 8; ++c) {
        half8 v = h8[c];
#pragma unroll
        for (int i = 0; i < 8; ++i) h[c * 8 + i] = (float)v[i];
    }
    float acc = b2[0];
#pragma unroll 1
    for (int j = 0; j < RH_; ++j) {
        float v = b1[j];
#pragma unroll
        for (int k = 0; k < RH_; ++k) v += w1[j * RH_ + k] * h[k];
        v = v > 0.0f ? v : 0.0f;
        acc += w2[j] * v;
    }
    out[n] = acc;
}

extern "C" void kernel_launch(void* const* d_in, const int* in_sizes, int n_in,
                              void* d_out, int out_size, void* d_ws, size_t ws_size,
                              hipStream_t stream) {
    const float* dyn     = (const float*)d_in[0];
    const float* statics = (const float*)d_in[1];
    const int*   ei      = (const int*)d_in[2];
    const float* w0      = (const float*)d_in[3];
    const float* b0      = (const float*)d_in[4];
    const float* w1      = (const float*)d_in[5];
    const float* b1      = (const float*)d_in[6];
    const float* wih     = (const float*)d_in[7];
    const float* whh     = (const float*)d_in[8];
    const float* bih     = (const float*)d_in[9];
    const float* bhh     = (const float*)d_in[10];
    const float* mw1     = (const float*)d_in[11];
    const float* mb1     = (const float*)d_in[12];
    const float* mw2     = (const float*)d_in[13];
    const float* mb2     = (const float*)d_in[14];
    const int* src = ei;
    const int* dst = ei + E_;

    char* ws = (char*)d_ws;
    auto alloc = [&](size_t elems) {        // 4B units, 256B-aligned
        elems = (elems + 63) & ~(size_t)63;
        void* p = ws; ws += elems * 4; return p;
    };
    const int NPAD = N_ + 64;               // tail block (49984..50047) padding
    int*    deg     = (int*)alloc(N_);
    int*    row_ptr = (int*)alloc(N_ + 4);
    int*    bsum    = (int*)alloc(256);
    int*    cursor  = (int*)alloc(N_);
    int2*   erec    = (int2*)alloc((size_t)E_ * 2);
    float*  dinv    = (float*)alloc(N_);
    float*  selfn   = (float*)alloc(N_);
    float*  h0s     = (float*)alloc(32 * N_);
    float*  csagg   = (float*)alloc(32 * N_);
    half_t* g1blk   = (half_t*)alloc((size_t)N_ * TB_ * GH_ / 2);   // f16 [N][8][32]
    half_t* xblk    = (half_t*)alloc(((size_t)TB_ * N_ + 64) * GH_ / 2); // f16 [8][N][32]+pad
    half_t* hA      = (half_t*)alloc((size_t)NPAD * RH_ / 2);       // f16 [Npad][64]
    float*  dynT    = (float*)alloc(64 * N_);
    float*  aT      = (float*)alloc(64 * N_);
    half_t* wTh     = (half_t*)alloc(96 * 192 / 2);

    auto cdiv = [](long long x, int b) { return (unsigned)((x + b - 1) / b); };
    const int B = 256;
    const unsigned NB = cdiv(N_, B);       // 196
    const unsigned GB = cdiv(N_, 64);      // 782

    hipMemsetAsync(deg, 0, N_ * sizeof(int), stream);
    hipMemsetAsync(cursor, 0, N_ * sizeof(int), stream);
    hipMemsetAsync(hA, 0, (size_t)NPAD * RH_ * sizeof(half_t), stream);

    k_transpose<<<cdiv(N_, 64), dim3(64, 4), 0, stream>>>(dyn, dynT);
    k_deg<<<cdiv(E_, B), B, 0, stream>>>(dst, deg);
    k_scanA<<<NB, B, 0, stream>>>(deg, row_ptr, bsum);
    k_scanB<<<1, B, 0, stream>>>(bsum, (int)NB);
    k_scanC<<<NB, B, 0, stream>>>(row_ptr, bsum);
    k_node_init<<<NB, B, 0, stream>>>(deg, statics, w0, dinv, selfn, h0s);
    k_scatter<<<cdiv(E_, B), B, 0, stream>>>(src, dst, dinv, row_ptr, cursor, erec);
    k_wt<<<cdiv(96 * 192, B), B, 0, stream>>>(wih, whh, wTh);
    k_gather32f<<<cdiv((long long)N_ * 8, B), B, 0, stream>>>(row_ptr, erec, selfn,
                                                              h0s, csagg);
    k_aall<<<cdiv((long long)N_ * 64, B), B, 0, stream>>>(row_ptr, erec, selfn,
                                                          dynT, aT);

    for (int p = 0; p < NP_; ++p) {
        k_g1blk<<<NB, B, 0, stream>>>(aT, csagg, w0, b0, w1, g1blk, p * TB_);
        k_gatherx<<<cdiv((long long)N_ * 8, B), B, 0, stream>>>(row_ptr, erec, selfn,
                                                                g1blk, b1, xblk);
        k_gruMM<<<GB, B, 0, stream>>>(xblk, wTh, bih, bhh, hA);
    }
    k_mlp<<<NB, B, 0, stream>>>(hA, mw1, mb1, mw2, mb2, (float*)d_out);
}

// Round 8
// 1942.936 us; speedup vs baseline: 35.4253x; 1.0652x over previous
//
#include <hip/hip_runtime.h>
#include <hip/hip_bf16.h>

#define T_   64
#define N_   50000
#define E_   1600000
#define GH_  32
#define RH_  64
#define TB_  16                    // timesteps per pass
#define NP_  (T_ / TB_)            // 4 passes

typedef _Float16 half_t;
typedef __attribute__((ext_vector_type(8))) _Float16 half8;
typedef __attribute__((ext_vector_type(4))) float f32x4;

static __device__ __forceinline__ float fast_sigmoid(float v) {
    float e = __expf(-v);
    return __builtin_amdgcn_rcpf(1.0f + e);
}
static __device__ __forceinline__ float fast_tanh(float v) {
    return 2.0f * fast_sigmoid(2.0f * v) - 1.0f;
}

// ---------- prologue ----------

// dyn [T,N] fp32 -> dynT [N,T] fp16
__global__ __launch_bounds__(256)
void k_transpose(const float* __restrict__ dyn, half_t* __restrict__ dynT) {
    __shared__ float tile[64][65];
    int n0 = blockIdx.x * 64;
    int tx = threadIdx.x, ty = threadIdx.y;
#pragma unroll
    for (int r = 0; r < 16; ++r) {
        int t = r * 4 + ty;
        int n = n0 + tx;
        tile[t][tx] = (n < N_) ? dyn[(size_t)t * N_ + n] : 0.0f;
    }
    __syncthreads();
#pragma unroll
    for (int r = 0; r < 16; ++r) {
        int nl = r * 4 + ty;
        int n = n0 + nl;
        if (n < N_) dynT[(size_t)n * 64 + tx] = (half_t)tile[tx][nl];
    }
}

__global__ void k_deg(const int* __restrict__ dst, int* __restrict__ deg) {
    int e = blockIdx.x * blockDim.x + threadIdx.x;
    if (e < E_) atomicAdd(&deg[dst[e]], 1);
}

// 3-phase parallel scan
__global__ __launch_bounds__(256)
void k_scanA(const int* __restrict__ deg, int* __restrict__ row_ptr,
             int* __restrict__ bsum) {
    __shared__ int buf[256];
    int tid = threadIdx.x;
    int i = blockIdx.x * 256 + tid;
    int v = (i < N_) ? deg[i] : 0;
    buf[tid] = v;
    __syncthreads();
#pragma unroll
    for (int off = 1; off < 256; off <<= 1) {
        int t = (tid >= off) ? buf[tid - off] : 0;
        __syncthreads();
        buf[tid] += t;
        __syncthreads();
    }
    if (i < N_) row_ptr[i + 1] = buf[tid];
    if (tid == 255) bsum[blockIdx.x] = buf[255];
}
__global__ __launch_bounds__(256)
void k_scanB(int* __restrict__ bsum, int nb) {
    __shared__ int buf[256];
    int tid = threadIdx.x;
    buf[tid] = (tid < nb) ? bsum[tid] : 0;
    __syncthreads();
#pragma unroll
    for (int off = 1; off < 256; off <<= 1) {
        int t = (tid >= off) ? buf[tid - off] : 0;
        __syncthreads();
        buf[tid] += t;
        __syncthreads();
    }
    if (tid < nb) bsum[tid] = (tid > 0) ? buf[tid - 1] : 0;
}
__global__ __launch_bounds__(256)
void k_scanC(int* __restrict__ row_ptr, const int* __restrict__ bsum) {
    int i = blockIdx.x * 256 + threadIdx.x;
    if (i == 0) row_ptr[0] = 0;
    if (i < N_) row_ptr[i + 1] += bsum[blockIdx.x];
}

__global__ __launch_bounds__(256)
void k_node_init(const int* __restrict__ deg,
                 const float* __restrict__ statics,
                 const float* __restrict__ w0,
                 float* __restrict__ dinv,
                 float* __restrict__ selfn,
                 float* __restrict__ h0s) {
    int n = blockIdx.x * blockDim.x + threadIdx.x;
    if (n >= N_) return;
    float d  = (float)deg[n] + 1.0f;
    float di = rsqrtf(d);
    dinv[n] = di;
    selfn[n] = di * di;
    float s[6];
#pragma unroll
    for (int j = 0; j < 6; ++j) s[j] = statics[n * 6 + j];
#pragma unroll
    for (int k = 0; k < GH_; ++k) {
        float v = 0.0f;
#pragma unroll
        for (int j = 0; j < 6; ++j) v += s[j] * w0[(1 + j) * GH_ + k];
        h0s[n * GH_ + k] = v;
    }
}

// interleaved 8-byte edge record {src, norm}
__global__ void k_scatter(const int* __restrict__ src, const int* __restrict__ dst,
                          const float* __restrict__ dinv,
                          const int* __restrict__ row_ptr, int* __restrict__ cursor,
                          int2* __restrict__ erec) {
    int e = blockIdx.x * blockDim.x + threadIdx.x;
    if (e >= E_) return;
    int s = src[e], d = dst[e];
    int pos = row_ptr[d] + atomicAdd(&cursor[d], 1);
    erec[pos] = make_int2(s, __float_as_int(dinv[s] * dinv[d]));
}

// combined GRU weight matrix, transposed, f16: wTh[k][m], k<32 -> wih, else whh
__global__ void k_wt(const float* __restrict__ wih, const float* __restrict__ whh,
                     half_t* __restrict__ wTh) {
    int idx = blockIdx.x * 256 + threadIdx.x;
    if (idx >= 96 * 192) return;
    int k = idx / 192, m = idx % 192;
    float v = (k < 32) ? wih[m * 32 + k] : whh[m * 64 + (k - 32)];
    wTh[idx] = (half_t)v;
}

// aT[n][t], wave per node, lane=t; dynT fp16 (128B per edge-read instr)
__global__ __launch_bounds__(256)
void k_aall(const int* __restrict__ row_ptr, const int2* __restrict__ erec,
            const float* __restrict__ selfn,
            const half_t* __restrict__ dynT, float* __restrict__ aT) {
    int gid = blockIdx.x * 256 + threadIdx.x;
    int n = gid >> 6, lane = gid & 63;
    if (n >= N_) return;
    float acc = selfn[n] * (float)dynT[(size_t)n * 64 + lane];
    int e0 = row_ptr[n], e1 = row_ptr[n + 1];
    int e = e0;
    for (; e < e1 && (e & 3); ++e) {
        int2 r = erec[e];
        acc += __int_as_float(r.y) * (float)dynT[(size_t)r.x * 64 + lane];
    }
    for (; e + 4 <= e1; e += 4) {
        int4 p0 = *(const int4*)(erec + e);
        int4 p1 = *(const int4*)(erec + e + 2);
        float v0 = (float)dynT[(size_t)p0.x * 64 + lane];
        float v1 = (float)dynT[(size_t)p0.z * 64 + lane];
        float v2 = (float)dynT[(size_t)p1.x * 64 + lane];
        float v3 = (float)dynT[(size_t)p1.z * 64 + lane];
        acc += __int_as_float(p0.y) * v0 + __int_as_float(p0.w) * v1
             + __int_as_float(p1.y) * v2 + __int_as_float(p1.w) * v3;
    }
    for (; e < e1; ++e) {
        int2 r = erec[e];
        acc += __int_as_float(r.y) * (float)dynT[(size_t)r.x * 64 + lane];
    }
    aT[(size_t)n * 64 + lane] = acc;
}

// fp32 gather (one-time, csagg): 8 lanes/node, float4
__global__ __launch_bounds__(256)
void k_gather32f(const int* __restrict__ row_ptr, const int2* __restrict__ erec,
                 const float* __restrict__ selfn,
                 const float* __restrict__ feat, float* __restrict__ out) {
    int gid = blockIdx.x * 256 + threadIdx.x;
    int n = gid >> 3, q = gid & 7;
    if (n >= N_) return;
    const float4* f4 = (const float4*)feat;
    float4 acc = f4[n * 8 + q];
    float sn = selfn[n];
    acc.x *= sn; acc.y *= sn; acc.z *= sn; acc.w *= sn;
    int e0 = row_ptr[n], e1 = row_ptr[n + 1];
    int e = e0;
    for (; e < e1 && (e & 3); ++e) {
        int2 r = erec[e];
        float nm = __int_as_float(r.y);
        float4 v = f4[(size_t)r.x * 8 + q];
        acc.x += nm * v.x; acc.y += nm * v.y; acc.z += nm * v.z; acc.w += nm * v.w;
    }
    for (; e + 4 <= e1; e += 4) {
        int4 p0 = *(const int4*)(erec + e);
        int4 p1 = *(const int4*)(erec + e + 2);
        float4 v0 = f4[(size_t)p0.x * 8 + q];
        float4 v1 = f4[(size_t)p0.z * 8 + q];
        float4 v2 = f4[(size_t)p1.x * 8 + q];
        float4 v3 = f4[(size_t)p1.z * 8 + q];
        float n0 = __int_as_float(p0.y), n1 = __int_as_float(p0.w);
        float n2 = __int_as_float(p1.y), n3 = __int_as_float(p1.w);
        acc.x += n0 * v0.x + n1 * v1.x + n2 * v2.x + n3 * v3.x;
        acc.y += n0 * v0.y + n1 * v1.y + n2 * v2.y + n3 * v3.y;
        acc.z += n0 * v0.z + n1 * v1.z + n2 * v2.z + n3 * v3.z;
        acc.w += n0 * v0.w + n1 * v1.w + n2 * v2.w + n3 * v3.w;
    }
    for (; e < e1; ++e) {
        int2 r = erec[e];
        float nm = __int_as_float(r.y);
        float4 v = f4[(size_t)r.x * 8 + q];
        acc.x += nm * v.x; acc.y += nm * v.y; acc.z += nm * v.z; acc.w += nm * v.w;
    }
    ((float4*)out)[n * 8 + q] = acc;
}

// ---------- per-pass (Tb=16 timesteps) ----------

// g1blk[n][u][32] fp16 for u = 0..15 (t = tb+u)
__global__ __launch_bounds__(256)
void k_g1blk(const float* __restrict__ aT, const float* __restrict__ csagg,
             const float* __restrict__ w0, const float* __restrict__ b0,
             const float* __restrict__ w1, half_t* __restrict__ g1blk, int tb) {
    int n = blockIdx.x * 256 + threadIdx.x;
    if (n >= N_) return;
    float c[GH_];
#pragma unroll
    for (int k = 0; k < GH_; ++k) c[k] = csagg[(size_t)n * GH_ + k] + b0[k];
    const float* at = aT + (size_t)n * 64 + tb;
    half8* outp = (half8*)(g1blk + (size_t)n * (TB_ * GH_));
#pragma unroll 1
    for (int u = 0; u < TB_; ++u) {
        float av = at[u];
        float h1[GH_];
#pragma unroll
        for (int k = 0; k < GH_; ++k) {
            float v = av * w0[k] + c[k];
            h1[k] = v > 0.0f ? v : 0.0f;
        }
        half8 o[4];
#pragma unroll
        for (int j = 0; j < GH_; ++j) {
            float v = 0.0f;
#pragma unroll
            for (int k = 0; k < GH_; ++k) v += h1[k] * w1[k * GH_ + j];
            o[j >> 3][j & 7] = (half_t)v;
        }
#pragma unroll
        for (int cc = 0; cc < 4; ++cc) outp[u * 4 + cc] = o[cc];
    }
}

// gather 16 timesteps in one pass: 16 lanes/node; 1KB contiguous per edge.
// Wave = 4 nodes; each instruction covers 4 x 256B random segments.
// lane q chunk u: chunk id c = q + 16u -> t = (q>>2) + 4u, kc = (q&3)*8.
// epilogue: xblk[t][n][k] = relu(agg + b1)  (fp16)
__global__ __launch_bounds__(256)
void k_gatherx(const int* __restrict__ row_ptr, const int2* __restrict__ erec,
               const float* __restrict__ selfn, const half_t* __restrict__ g1blk,
               const float* __restrict__ b1, half_t* __restrict__ xblk) {
    int gid = blockIdx.x * 256 + threadIdx.x;
    int n = gid >> 4, q = gid & 15;
    if (n >= N_) return;
    const half8* g8 = (const half8*)g1blk;   // node row = 64 chunks of 16B
    float acc[4][8];
    {
        float sn = selfn[n];
#pragma unroll
        for (int u = 0; u < 4; ++u) {
            half8 sv = g8[(size_t)n * 64 + q + 16 * u];
#pragma unroll
            for (int i = 0; i < 8; ++i) acc[u][i] = sn * (float)sv[i];
        }
    }
    int e0 = row_ptr[n], e1 = row_ptr[n + 1];
    int e = e0;
    for (; e < e1 && (e & 3); ++e) {
        int2 r = erec[e];
        float nm = __int_as_float(r.y);
        size_t base = (size_t)r.x * 64 + q;
#pragma unroll
        for (int u = 0; u < 4; ++u) {
            half8 v = g8[base + 16 * u];
#pragma unroll
            for (int i = 0; i < 8; ++i) acc[u][i] += nm * (float)v[i];
        }
    }
    for (; e + 4 <= e1; e += 4) {
        int4 p0 = *(const int4*)(erec + e);
        int4 p1 = *(const int4*)(erec + e + 2);
        size_t b0a = (size_t)p0.x * 64 + q;
        size_t b1a = (size_t)p0.z * 64 + q;
        size_t b2a = (size_t)p1.x * 64 + q;
        size_t b3a = (size_t)p1.z * 64 + q;
        float n0 = __int_as_float(p0.y), n1 = __int_as_float(p0.w);
        float n2 = __int_as_float(p1.y), n3 = __int_as_float(p1.w);
        half8 v0[4], v1[4], v2[4], v3[4];
#pragma unroll
        for (int u = 0; u < 4; ++u) {
            v0[u] = g8[b0a + 16 * u];
            v1[u] = g8[b1a + 16 * u];
            v2[u] = g8[b2a + 16 * u];
            v3[u] = g8[b3a + 16 * u];
        }
#pragma unroll
        for (int u = 0; u < 4; ++u)
#pragma unroll
            for (int i = 0; i < 8; ++i)
                acc[u][i] += n0 * (float)v0[u][i] + n1 * (float)v1[u][i]
                           + n2 * (float)v2[u][i] + n3 * (float)v3[u][i];
    }
    for (; e < e1; ++e) {
        int2 r = erec[e];
        float nm = __int_as_float(r.y);
        size_t base = (size_t)r.x * 64 + q;
#pragma unroll
        for (int u = 0; u < 4; ++u) {
            half8 v = g8[base + 16 * u];
#pragma unroll
            for (int i = 0; i < 8; ++i) acc[u][i] += nm * (float)v[i];
        }
    }
    int kc = (q & 3) * 8;
    const float* bb = b1 + kc;
#pragma unroll
    for (int u = 0; u < 4; ++u) {
        int t = (q >> 2) + 4 * u;
        half8 o;
#pragma unroll
        for (int i = 0; i < 8; ++i)
            o[i] = (half_t)fmaxf(acc[u][i] + bb[i], 0.0f);
        *(half8*)(xblk + ((size_t)t * N_ + n) * GH_ + kc) = o;
    }
}

// ---------- MFMA GRU: 16 timesteps fused, h in LDS f16 ----------
#define HSTR_ 72   // hL row stride in f16: 144B = 16B-aligned, 2-way banks (free)
__global__ __launch_bounds__(256, 2)
void k_gruMM(const half_t* __restrict__ xblk,   // [TB][N][32] f16
             const half_t* __restrict__ wTh,    // [96][192] f16
             const float* __restrict__ bih, const float* __restrict__ bhh,
             half_t* __restrict__ hA) {         // [Npad][64] f16
    __shared__ half_t wL[96 * 192];
    __shared__ half_t hL[64 * HSTR_];
    int tid = threadIdx.x;
    int nb0 = blockIdx.x * 64;
    {
        const half8* s = (const half8*)wTh;
        half8* d = (half8*)wL;
        for (int i = tid; i < 96 * 192 / 8; i += 256) d[i] = s[i];
    }
    for (int i = tid; i < 64 * 8; i += 256) {
        int node = i >> 3, ch = i & 7;
        half8 v = *(const half8*)(hA + (size_t)(nb0 + node) * RH_ + ch * 8);
        *(half8*)(hL + node * HSTR_ + ch * 8) = v;
    }
    __syncthreads();
    int lane = tid & 63;
    int wv = tid >> 6;
    int c16 = lane & 15, q = lane >> 4;
    half8 bfr[3][12];
#pragma unroll
    for (int c = 0; c < 3; ++c)
#pragma unroll
        for (int nt = 0; nt < 12; ++nt) {
#pragma unroll
            for (int j = 0; j < 8; ++j)
                bfr[c][nt][j] = wL[(c * 32 + q * 8 + j) * 192 + nt * 16 + c16];
        }
    float br[4], bz[4], bnx[4], bnh[4];
#pragma unroll
    for (int jt = 0; jt < 4; ++jt) {
        int j = jt * 16 + c16;
        br[jt]  = bih[j] + bhh[j];
        bz[jt]  = bih[64 + j] + bhh[64 + j];
        bnx[jt] = bih[128 + j];
        bnh[jt] = bhh[128 + j];
    }
    int mrow = wv * 16 + c16;
    const half_t* hrow = hL + mrow * HSTR_;
    const f32x4 zero = {0.0f, 0.0f, 0.0f, 0.0f};
#pragma unroll 1
    for (int u = 0; u < TB_; ++u) {
        half8 ax  = *(const half8*)(xblk + ((size_t)u * N_ + nb0 + mrow) * GH_ + q * 8);
        half8 ah0 = *(const half8*)(hrow + q * 8);
        half8 ah1 = *(const half8*)(hrow + 32 + q * 8);
        f32x4 Crz[8], Cnx[4], Cnh[4];
#pragma unroll
        for (int nt = 0; nt < 8; ++nt) {
            Crz[nt] = __builtin_amdgcn_mfma_f32_16x16x32_f16(ax,  bfr[0][nt], zero,     0, 0, 0);
            Crz[nt] = __builtin_amdgcn_mfma_f32_16x16x32_f16(ah0, bfr[1][nt], Crz[nt], 0, 0, 0);
            Crz[nt] = __builtin_amdgcn_mfma_f32_16x16x32_f16(ah1, bfr[2][nt], Crz[nt], 0, 0, 0);
        }
#pragma unroll
        for (int nt = 0; nt < 4; ++nt) {
            Cnx[nt] = __builtin_amdgcn_mfma_f32_16x16x32_f16(ax,  bfr[0][8 + nt], zero,     0, 0, 0);
            Cnh[nt] = __builtin_amdgcn_mfma_f32_16x16x32_f16(ah0, bfr[1][8 + nt], zero,     0, 0, 0);
            Cnh[nt] = __builtin_amdgcn_mfma_f32_16x16x32_f16(ah1, bfr[2][8 + nt], Cnh[nt], 0, 0, 0);
        }
#pragma unroll
        for (int jt = 0; jt < 4; ++jt) {
#pragma unroll
            for (int reg = 0; reg < 4; ++reg) {
                int nl = wv * 16 + q * 4 + reg;
                int jj = jt * 16 + c16;
                float hold = (float)hL[nl * HSTR_ + jj];
                float r  = fast_sigmoid(Crz[jt][reg] + br[jt]);
                float z  = fast_sigmoid(Crz[4 + jt][reg] + bz[jt]);
                float cd = fast_tanh(Cnx[jt][reg] + bnx[jt] + r * (Cnh[jt][reg] + bnh[jt]));
                hL[nl * HSTR_ + jj] = (half_t)((1.0f - z) * cd + z * hold);
            }
        }
    }
    __syncthreads();
    for (int i = tid; i < 64 * 8; i += 256) {
        int node = i >> 3, ch = i & 7;
        half8 v = *(const half8*)(hL + node * HSTR_ + ch * 8);
        *(half8*)(hA + (size_t)(nb0 + node) * RH_ + ch * 8) = v;
    }
}

__global__ __launch_bounds__(256)
void k_mlp(const half_t* __restrict__ hA, const float* __restrict__ w1,
           const float* __restrict__ b1, const float* __restrict__ w2,
           const float* __restrict__ b2, float* __restrict__ out) {
    int n = blockIdx.x * blockDim.x + threadIdx.x;
    if (n >= N_) return;
    float h[RH_];
    const half8* h8 = (const half8*)(hA + (size_t)n * RH_);
#pragma unroll
    for (int c = 0; c < 8; ++c) {
        half8 v = h8[c];
#pragma unroll
        for (int i = 0; i < 8; ++i) h[c * 8 + i] = (float)v[i];
    }
    float acc = b2[0];
#pragma unroll 1
    for (int j = 0; j < RH_; ++j) {
        float v = b1[j];
#pragma unroll
        for (int k = 0; k < RH_; ++k) v += w1[j * RH_ + k] * h[k];
        v = v > 0.0f ? v : 0.0f;
        acc += w2[j] * v;
    }
    out[n] = acc;
}

extern "C" void kernel_launch(void* const* d_in, const int* in_sizes, int n_in,
                              void* d_out, int out_size, void* d_ws, size_t ws_size,
                              hipStream_t stream) {
    const float* dyn     = (const float*)d_in[0];
    const float* statics = (const float*)d_in[1];
    const int*   ei      = (const int*)d_in[2];
    const float* w0      = (const float*)d_in[3];
    const float* b0      = (const float*)d_in[4];
    const float* w1      = (const float*)d_in[5];
    const float* b1      = (const float*)d_in[6];
    const float* wih     = (const float*)d_in[7];
    const float* whh     = (const float*)d_in[8];
    const float* bih     = (const float*)d_in[9];
    const float* bhh     = (const float*)d_in[10];
    const float* mw1     = (const float*)d_in[11];
    const float* mb1     = (const float*)d_in[12];
    const float* mw2     = (const float*)d_in[13];
    const float* mb2     = (const float*)d_in[14];
    const int* src = ei;
    const int* dst = ei + E_;

    char* ws = (char*)d_ws;
    auto alloc = [&](size_t elems) {        // 4B units, 256B-aligned
        elems = (elems + 63) & ~(size_t)63;
        void* p = ws; ws += elems * 4; return p;
    };
    const int NPAD = N_ + 64;
    int*    deg     = (int*)alloc(N_);
    int*    row_ptr = (int*)alloc(N_ + 4);
    int*    bsum    = (int*)alloc(256);
    int*    cursor  = (int*)alloc(N_);
    int2*   erec    = (int2*)alloc((size_t)E_ * 2);
    float*  dinv    = (float*)alloc(N_);
    float*  selfn   = (float*)alloc(N_);
    float*  h0s     = (float*)alloc(32 * N_);
    float*  csagg   = (float*)alloc(32 * N_);
    half_t* g1blk   = (half_t*)alloc((size_t)N_ * TB_ * GH_ / 2);   // f16 [N][16][32]
    half_t* xblk    = (half_t*)alloc(((size_t)TB_ * N_ + 64) * GH_ / 2); // f16 [16][N][32]
    half_t* hA      = (half_t*)alloc((size_t)NPAD * RH_ / 2);       // f16 [Npad][64]
    half_t* dynT    = (half_t*)alloc((size_t)N_ * 64 / 2);          // f16 [N][64]
    float*  aT      = (float*)alloc(64 * N_);
    half_t* wTh     = (half_t*)alloc(96 * 192 / 2);

    auto cdiv = [](long long x, int b) { return (unsigned)((x + b - 1) / b); };
    const int B = 256;
    const unsigned NB = cdiv(N_, B);       // 196
    const unsigned GB = cdiv(N_, 64);      // 782

    hipMemsetAsync(deg, 0, N_ * sizeof(int), stream);
    hipMemsetAsync(cursor, 0, N_ * sizeof(int), stream);
    hipMemsetAsync(hA, 0, (size_t)NPAD * RH_ * sizeof(half_t), stream);

    k_transpose<<<cdiv(N_, 64), dim3(64, 4), 0, stream>>>(dyn, dynT);
    k_deg<<<cdiv(E_, B), B, 0, stream>>>(dst, deg);
    k_scanA<<<NB, B, 0, stream>>>(deg, row_ptr, bsum);
    k_scanB<<<1, B, 0, stream>>>(bsum, (int)NB);
    k_scanC<<<NB, B, 0, stream>>>(row_ptr, bsum);
    k_node_init<<<NB, B, 0, stream>>>(deg, statics, w0, dinv, selfn, h0s);
    k_scatter<<<cdiv(E_, B), B, 0, stream>>>(src, dst, dinv, row_ptr, cursor, erec);
    k_wt<<<cdiv(96 * 192, B), B, 0, stream>>>(wih, whh, wTh);
    k_gather32f<<<cdiv((long long)N_ * 8, B), B, 0, stream>>>(row_ptr, erec, selfn,
                                                              h0s, csagg);
    k_aall<<<cdiv((long long)N_ * 64, B), B, 0, stream>>>(row_ptr, erec, selfn,
                                                          dynT, aT);

    for (int p = 0; p < NP_; ++p) {
        k_g1blk<<<NB, B, 0, stream>>>(aT, csagg, w0, b0, w1, g1blk, p * TB_);
        k_gatherx<<<cdiv((long long)N_ * 16, B), B, 0, stream>>>(row_ptr, erec, selfn,
                                                                 g1blk, b1, xblk);
        k_gruMM<<<GB, B, 0, stream>>>(xblk, wTh, bih, bhh, hA);
    }
    k_mlp<<<NB, B, 0, stream>>>(hA, mw1, mb1, mw2, mb2, (float*)d_out);
}

// Round 9
// 1822.328 us; speedup vs baseline: 37.7698x; 1.0662x over previous
//
#include <hip/hip_runtime.h>
#include <hip/hip_bf16.h>

#define T_   64
#define N_   50000
#define E_   1600000
#define GH_  32
#define RH_  64
#define TB_  16                    // timesteps per pass
#define NP_  (T_ / TB_)            // 4 passes
#define NT_  13                    // src tiles (src>>12), stride 16

typedef _Float16 half_t;
typedef __attribute__((ext_vector_type(8))) _Float16 half8;
typedef __attribute__((ext_vector_type(4))) float f32x4;

static __device__ __forceinline__ float fast_sigmoid(float v) {
    float e = __expf(-v);
    return __builtin_amdgcn_rcpf(1.0f + e);
}
static __device__ __forceinline__ float fast_tanh(float v) {
    return 2.0f * fast_sigmoid(2.0f * v) - 1.0f;
}

// ---------- prologue ----------

// dyn [T,N] fp32 -> dynT [N,T] fp16
__global__ __launch_bounds__(256)
void k_transpose(const float* __restrict__ dyn, half_t* __restrict__ dynT) {
    __shared__ float tile[64][65];
    int n0 = blockIdx.x * 64;
    int tx = threadIdx.x, ty = threadIdx.y;
#pragma unroll
    for (int r = 0; r < 16; ++r) {
        int t = r * 4 + ty;
        int n = n0 + tx;
        tile[t][tx] = (n < N_) ? dyn[(size_t)t * N_ + n] : 0.0f;
    }
    __syncthreads();
#pragma unroll
    for (int r = 0; r < 16; ++r) {
        int nl = r * 4 + ty;
        int n = n0 + nl;
        if (n < N_) dynT[(size_t)n * 64 + tx] = (half_t)tile[tx][nl];
    }
}

// per-(dst, src-tile) histogram
__global__ void k_hist(const int* __restrict__ src, const int* __restrict__ dst,
                       int* __restrict__ cnt) {
    int e = blockIdx.x * blockDim.x + threadIdx.x;
    if (e >= E_) return;
    atomicAdd(&cnt[dst[e] * 16 + (src[e] >> 12)], 1);
}

__global__ __launch_bounds__(256)
void k_degsum(const int* __restrict__ cnt, int* __restrict__ deg) {
    int n = blockIdx.x * 256 + threadIdx.x;
    if (n >= N_) return;
    const int4* c4 = (const int4*)(cnt + n * 16);
    int s = 0;
#pragma unroll
    for (int i = 0; i < 4; ++i) {
        int4 v = c4[i];
        s += v.x + v.y + v.z + v.w;
    }
    deg[n] = s;
}

// 3-phase parallel scan -> row_ptr
__global__ __launch_bounds__(256)
void k_scanA(const int* __restrict__ deg, int* __restrict__ row_ptr,
             int* __restrict__ bsum) {
    __shared__ int buf[256];
    int tid = threadIdx.x;
    int i = blockIdx.x * 256 + tid;
    int v = (i < N_) ? deg[i] : 0;
    buf[tid] = v;
    __syncthreads();
#pragma unroll
    for (int off = 1; off < 256; off <<= 1) {
        int t = (tid >= off) ? buf[tid - off] : 0;
        __syncthreads();
        buf[tid] += t;
        __syncthreads();
    }
    if (i < N_) row_ptr[i + 1] = buf[tid];
    if (tid == 255) bsum[blockIdx.x] = buf[255];
}
__global__ __launch_bounds__(256)
void k_scanB(int* __restrict__ bsum, int nb) {
    __shared__ int buf[256];
    int tid = threadIdx.x;
    buf[tid] = (tid < nb) ? bsum[tid] : 0;
    __syncthreads();
#pragma unroll
    for (int off = 1; off < 256; off <<= 1) {
        int t = (tid >= off) ? buf[tid - off] : 0;
        __syncthreads();
        buf[tid] += t;
        __syncthreads();
    }
    if (tid < nb) bsum[tid] = (tid > 0) ? buf[tid - 1] : 0;
}
__global__ __launch_bounds__(256)
void k_scanC(int* __restrict__ row_ptr, const int* __restrict__ bsum) {
    int i = blockIdx.x * 256 + threadIdx.x;
    if (i == 0) row_ptr[0] = 0;
    if (i < N_) row_ptr[i + 1] += bsum[blockIdx.x];
}

// rp2[n][t] = row_ptr[n] + prefix(cnt[n][0..t)); zero cnt (reused as cursor)
__global__ __launch_bounds__(256)
void k_rowscan(const int* __restrict__ row_ptr, int* __restrict__ cnt,
               int* __restrict__ rp2) {
    int n = blockIdx.x * 256 + threadIdx.x;
    if (n >= N_) return;
    int run = row_ptr[n];
#pragma unroll
    for (int t = 0; t < 16; ++t) {
        int c = cnt[n * 16 + t];
        rp2[n * 16 + t] = run;
        run += c;
        cnt[n * 16 + t] = 0;
    }
}

__global__ __launch_bounds__(256)
void k_node_init(const int* __restrict__ deg,
                 const float* __restrict__ statics,
                 const float* __restrict__ w0,
                 float* __restrict__ dinv,
                 float* __restrict__ selfn,
                 half_t* __restrict__ h0s) {          // [N,32] f16
    int n = blockIdx.x * blockDim.x + threadIdx.x;
    if (n >= N_) return;
    float d  = (float)deg[n] + 1.0f;
    float di = rsqrtf(d);
    dinv[n] = di;
    selfn[n] = di * di;
    float s[6];
#pragma unroll
    for (int j = 0; j < 6; ++j) s[j] = statics[n * 6 + j];
    half8 o[4];
#pragma unroll
    for (int k = 0; k < GH_; ++k) {
        float v = 0.0f;
#pragma unroll
        for (int j = 0; j < 6; ++j) v += s[j] * w0[(1 + j) * GH_ + k];
        o[k >> 3][k & 7] = (half_t)v;
    }
    half8* dst8 = (half8*)(h0s + (size_t)n * GH_);
#pragma unroll
    for (int c = 0; c < 4; ++c) dst8[c] = o[c];
}

// tile-ordered scatter: 8-byte record {src, norm}
__global__ void k_scatter2(const int* __restrict__ src, const int* __restrict__ dst,
                           const float* __restrict__ dinv,
                           const int* __restrict__ rp2, int* __restrict__ cnt,
                           int2* __restrict__ erec) {
    int e = blockIdx.x * blockDim.x + threadIdx.x;
    if (e >= E_) return;
    int s = src[e], d = dst[e];
    int slot = d * 16 + (s >> 12);
    int pos = rp2[slot] + atomicAdd(&cnt[slot], 1);
    erec[pos] = make_int2(s, __float_as_int(dinv[s] * dinv[d]));
}

// combined GRU weights, transposed f16
__global__ void k_wt(const float* __restrict__ wih, const float* __restrict__ whh,
                     half_t* __restrict__ wTh) {
    int idx = blockIdx.x * 256 + threadIdx.x;
    if (idx >= 96 * 192) return;
    int k = idx / 192, m = idx % 192;
    float v = (k < 32) ? wih[m * 32 + k] : whh[m * 64 + (k - 32)];
    wTh[idx] = (half_t)v;
}

// aT[n][t], wave per node, lane=t; dynT f16
__global__ __launch_bounds__(256)
void k_aall(const int* __restrict__ row_ptr, const int2* __restrict__ erec,
            const float* __restrict__ selfn,
            const half_t* __restrict__ dynT, float* __restrict__ aT) {
    int gid = blockIdx.x * 256 + threadIdx.x;
    int n = gid >> 6, lane = gid & 63;
    if (n >= N_) return;
    float acc = selfn[n] * (float)dynT[(size_t)n * 64 + lane];
    int e0 = row_ptr[n], e1 = row_ptr[n + 1];
    int e = e0;
    for (; e < e1 && (e & 3); ++e) {
        int2 r = erec[e];
        acc += __int_as_float(r.y) * (float)dynT[(size_t)r.x * 64 + lane];
    }
    for (; e + 4 <= e1; e += 4) {
        int4 p0 = *(const int4*)(erec + e);
        int4 p1 = *(const int4*)(erec + e + 2);
        float v0 = (float)dynT[(size_t)p0.x * 64 + lane];
        float v1 = (float)dynT[(size_t)p0.z * 64 + lane];
        float v2 = (float)dynT[(size_t)p1.x * 64 + lane];
        float v3 = (float)dynT[(size_t)p1.z * 64 + lane];
        acc += __int_as_float(p0.y) * v0 + __int_as_float(p0.w) * v1
             + __int_as_float(p1.y) * v2 + __int_as_float(p1.w) * v3;
    }
    for (; e < e1; ++e) {
        int2 r = erec[e];
        acc += __int_as_float(r.y) * (float)dynT[(size_t)r.x * 64 + lane];
    }
    aT[(size_t)n * 64 + lane] = acc;
}

// one-time csagg gather: f16 h0s, 4 lanes/node, half8; out f32 csagg
__global__ __launch_bounds__(256)
void k_gather16s(const int* __restrict__ row_ptr, const int2* __restrict__ erec,
                 const float* __restrict__ selfn, const half_t* __restrict__ h0s,
                 float* __restrict__ csagg) {
    int gid = blockIdx.x * 256 + threadIdx.x;
    int n = gid >> 2, q = gid & 3;
    if (n >= N_) return;
    const half8* f8 = (const half8*)h0s;
    float acc[8];
    {
        half8 sv = f8[(size_t)n * 4 + q];
        float sn = selfn[n];
#pragma unroll
        for (int i = 0; i < 8; ++i) acc[i] = sn * (float)sv[i];
    }
    int e0 = row_ptr[n], e1 = row_ptr[n + 1];
    int e = e0;
    for (; e < e1 && (e & 3); ++e) {
        int2 r = erec[e];
        float nm = __int_as_float(r.y);
        half8 v = f8[(size_t)r.x * 4 + q];
#pragma unroll
        for (int i = 0; i < 8; ++i) acc[i] += nm * (float)v[i];
    }
    for (; e + 4 <= e1; e += 4) {
        int4 p0 = *(const int4*)(erec + e);
        int4 p1 = *(const int4*)(erec + e + 2);
        half8 v0 = f8[(size_t)p0.x * 4 + q];
        half8 v1 = f8[(size_t)p0.z * 4 + q];
        half8 v2 = f8[(size_t)p1.x * 4 + q];
        half8 v3 = f8[(size_t)p1.z * 4 + q];
        float n0 = __int_as_float(p0.y), n1 = __int_as_float(p0.w);
        float n2 = __int_as_float(p1.y), n3 = __int_as_float(p1.w);
#pragma unroll
        for (int i = 0; i < 8; ++i)
            acc[i] += n0 * (float)v0[i] + n1 * (float)v1[i]
                    + n2 * (float)v2[i] + n3 * (float)v3[i];
    }
    for (; e < e1; ++e) {
        int2 r = erec[e];
        float nm = __int_as_float(r.y);
        half8 v = f8[(size_t)r.x * 4 + q];
#pragma unroll
        for (int i = 0; i < 8; ++i) acc[i] += nm * (float)v[i];
    }
    float4* out = (float4*)(csagg + (size_t)n * GH_ + q * 8);
    out[0] = make_float4(acc[0], acc[1], acc[2], acc[3]);
    out[1] = make_float4(acc[4], acc[5], acc[6], acc[7]);
}

// ---------- per-pass ----------

static __device__ __forceinline__
void g1_body(int bid, int tb, const float* __restrict__ aT,
             const float* __restrict__ csagg, const float* __restrict__ w0,
             const float* __restrict__ b0, const float* __restrict__ w1,
             half_t* __restrict__ g1blk) {
    int n = bid * 256 + threadIdx.x;
    if (n >= N_) return;
    float c[GH_];
#pragma unroll
    for (int k = 0; k < GH_; ++k) c[k] = csagg[(size_t)n * GH_ + k] + b0[k];
    const float* at = aT + (size_t)n * 64 + tb;
    half8* outp = (half8*)(g1blk + (size_t)n * (TB_ * GH_));
#pragma unroll 1
    for (int u = 0; u < TB_; ++u) {
        float av = at[u];
        float h1[GH_];
#pragma unroll
        for (int k = 0; k < GH_; ++k) {
            float v = av * w0[k] + c[k];
            h1[k] = v > 0.0f ? v : 0.0f;
        }
        half8 o[4];
#pragma unroll
        for (int j = 0; j < GH_; ++j) {
            float v = 0.0f;
#pragma unroll
            for (int k = 0; k < GH_; ++k) v += h1[k] * w1[k * GH_ + j];
            o[j >> 3][j & 7] = (half_t)v;
        }
#pragma unroll
        for (int cc = 0; cc < 4; ++cc) outp[u * 4 + cc] = o[cc];
    }
}

// t=0 g1 only
__global__ __launch_bounds__(256)
void k_g1blk(const float* __restrict__ aT, const float* __restrict__ csagg,
             const float* __restrict__ w0, const float* __restrict__ b0,
             const float* __restrict__ w1, half_t* __restrict__ g1blk, int tb) {
    g1_body(blockIdx.x, tb, aT, csagg, w0, b0, w1, g1blk);
}

// gather 16 timesteps: 16 lanes/node; 1KB contiguous per edge (tile-sorted CSR)
__global__ __launch_bounds__(256)
void k_gatherx(const int* __restrict__ row_ptr, const int2* __restrict__ erec,
               const float* __restrict__ selfn, const half_t* __restrict__ g1blk,
               const float* __restrict__ b1, half_t* __restrict__ xblk) {
    int gid = blockIdx.x * 256 + threadIdx.x;
    int n = gid >> 4, q = gid & 15;
    if (n >= N_) return;
    const half8* g8 = (const half8*)g1blk;   // node row = 64 chunks of 16B
    float acc[4][8];
    {
        float sn = selfn[n];
#pragma unroll
        for (int u = 0; u < 4; ++u) {
            half8 sv = g8[(size_t)n * 64 + q + 16 * u];
#pragma unroll
            for (int i = 0; i < 8; ++i) acc[u][i] = sn * (float)sv[i];
        }
    }
    int e0 = row_ptr[n], e1 = row_ptr[n + 1];
    int e = e0;
    for (; e < e1 && (e & 3); ++e) {
        int2 r = erec[e];
        float nm = __int_as_float(r.y);
        size_t base = (size_t)r.x * 64 + q;
#pragma unroll
        for (int u = 0; u < 4; ++u) {
            half8 v = g8[base + 16 * u];
#pragma unroll
            for (int i = 0; i < 8; ++i) acc[u][i] += nm * (float)v[i];
        }
    }
    for (; e + 4 <= e1; e += 4) {
        int4 p0 = *(const int4*)(erec + e);
        int4 p1 = *(const int4*)(erec + e + 2);
        size_t b0a = (size_t)p0.x * 64 + q;
        size_t b1a = (size_t)p0.z * 64 + q;
        size_t b2a = (size_t)p1.x * 64 + q;
        size_t b3a = (size_t)p1.z * 64 + q;
        float n0 = __int_as_float(p0.y), n1 = __int_as_float(p0.w);
        float n2 = __int_as_float(p1.y), n3 = __int_as_float(p1.w);
        half8 v0[4], v1[4], v2[4], v3[4];
#pragma unroll
        for (int u = 0; u < 4; ++u) {
            v0[u] = g8[b0a + 16 * u];
            v1[u] = g8[b1a + 16 * u];
            v2[u] = g8[b2a + 16 * u];
            v3[u] = g8[b3a + 16 * u];
        }
#pragma unroll
        for (int u = 0; u < 4; ++u)
#pragma unroll
            for (int i = 0; i < 8; ++i)
                acc[u][i] += n0 * (float)v0[u][i] + n1 * (float)v1[u][i]
                           + n2 * (float)v2[u][i] + n3 * (float)v3[u][i];
    }
    for (; e < e1; ++e) {
        int2 r = erec[e];
        float nm = __int_as_float(r.y);
        size_t base = (size_t)r.x * 64 + q;
#pragma unroll
        for (int u = 0; u < 4; ++u) {
            half8 v = g8[base + 16 * u];
#pragma unroll
            for (int i = 0; i < 8; ++i) acc[u][i] += nm * (float)v[i];
        }
    }
    int kc = (q & 3) * 8;
    const float* bb = b1 + kc;
#pragma unroll
    for (int u = 0; u < 4; ++u) {
        int t = (q >> 2) + 4 * u;
        half8 o;
#pragma unroll
        for (int i = 0; i < 8; ++i)
            o[i] = (half_t)fmaxf(acc[u][i] + bb[i], 0.0f);
        *(half8*)(xblk + ((size_t)t * N_ + n) * GH_ + kc) = o;
    }
}

// ---------- fused MFMA GRU (pass p) + g1blk (pass p+1) ----------
#define HSTR_ 72
#define GB_   782                  // cdiv(N,64) gru blocks
#define NB_   196                  // cdiv(N,256) g1 blocks
__global__ __launch_bounds__(256, 2)
void k_gru_g1(const half_t* __restrict__ xblk, const half_t* __restrict__ wTh,
              const float* __restrict__ bih, const float* __restrict__ bhh,
              half_t* __restrict__ hA,
              const float* __restrict__ aT, const float* __restrict__ csagg,
              const float* __restrict__ w0, const float* __restrict__ b0,
              const float* __restrict__ w1, half_t* __restrict__ g1blk,
              int tb_next, int do_g1) {
    __shared__ half_t wL[96 * 192];
    __shared__ half_t hL[64 * HSTR_];
    if ((int)blockIdx.x >= GB_) {
        if (do_g1)
            g1_body((int)blockIdx.x - GB_, tb_next, aT, csagg, w0, b0, w1, g1blk);
        return;
    }
    int tid = threadIdx.x;
    int nb0 = blockIdx.x * 64;
    {
        const half8* s = (const half8*)wTh;
        half8* d = (half8*)wL;
        for (int i = tid; i < 96 * 192 / 8; i += 256) d[i] = s[i];
    }
    for (int i = tid; i < 64 * 8; i += 256) {
        int node = i >> 3, ch = i & 7;
        half8 v = *(const half8*)(hA + (size_t)(nb0 + node) * RH_ + ch * 8);
        *(half8*)(hL + node * HSTR_ + ch * 8) = v;
    }
    __syncthreads();
    int lane = tid & 63;
    int wv = tid >> 6;
    int c16 = lane & 15, q = lane >> 4;
    half8 bfr[3][12];
#pragma unroll
    for (int c = 0; c < 3; ++c)
#pragma unroll
        for (int nt = 0; nt < 12; ++nt) {
#pragma unroll
            for (int j = 0; j < 8; ++j)
                bfr[c][nt][j] = wL[(c * 32 + q * 8 + j) * 192 + nt * 16 + c16];
        }
    float br[4], bz[4], bnx[4], bnh[4];
#pragma unroll
    for (int jt = 0; jt < 4; ++jt) {
        int j = jt * 16 + c16;
        br[jt]  = bih[j] + bhh[j];
        bz[jt]  = bih[64 + j] + bhh[64 + j];
        bnx[jt] = bih[128 + j];
        bnh[jt] = bhh[128 + j];
    }
    int mrow = wv * 16 + c16;
    const half_t* hrow = hL + mrow * HSTR_;
    const f32x4 zero = {0.0f, 0.0f, 0.0f, 0.0f};
#pragma unroll 1
    for (int u = 0; u < TB_; ++u) {
        half8 ax  = *(const half8*)(xblk + ((size_t)u * N_ + nb0 + mrow) * GH_ + q * 8);
        half8 ah0 = *(const half8*)(hrow + q * 8);
        half8 ah1 = *(const half8*)(hrow + 32 + q * 8);
        f32x4 Crz[8], Cnx[4], Cnh[4];
#pragma unroll
        for (int nt = 0; nt < 8; ++nt) {
            Crz[nt] = __builtin_amdgcn_mfma_f32_16x16x32_f16(ax,  bfr[0][nt], zero,     0, 0, 0);
            Crz[nt] = __builtin_amdgcn_mfma_f32_16x16x32_f16(ah0, bfr[1][nt], Crz[nt], 0, 0, 0);
            Crz[nt] = __builtin_amdgcn_mfma_f32_16x16x32_f16(ah1, bfr[2][nt], Crz[nt], 0, 0, 0);
        }
#pragma unroll
        for (int nt = 0; nt < 4; ++nt) {
            Cnx[nt] = __builtin_amdgcn_mfma_f32_16x16x32_f16(ax,  bfr[0][8 + nt], zero,     0, 0, 0);
            Cnh[nt] = __builtin_amdgcn_mfma_f32_16x16x32_f16(ah0, bfr[1][8 + nt], zero,     0, 0, 0);
            Cnh[nt] = __builtin_amdgcn_mfma_f32_16x16x32_f16(ah1, bfr[2][8 + nt], Cnh[nt], 0, 0, 0);
        }
#pragma unroll
        for (int jt = 0; jt < 4; ++jt) {
#pragma unroll
            for (int reg = 0; reg < 4; ++reg) {
                int nl = wv * 16 + q * 4 + reg;
                int jj = jt * 16 + c16;
                float hold = (float)hL[nl * HSTR_ + jj];
                float r  = fast_sigmoid(Crz[jt][reg] + br[jt]);
                float z  = fast_sigmoid(Crz[4 + jt][reg] + bz[jt]);
                float cd = fast_tanh(Cnx[jt][reg] + bnx[jt] + r * (Cnh[jt][reg] + bnh[jt]));
                hL[nl * HSTR_ + jj] = (half_t)((1.0f - z) * cd + z * hold);
            }
        }
    }
    __syncthreads();
    for (int i = tid; i < 64 * 8; i += 256) {
        int node = i >> 3, ch = i & 7;
        half8 v = *(const half8*)(hL + node * HSTR_ + ch * 8);
        *(half8*)(hA + (size_t)(nb0 + node) * RH_ + ch * 8) = v;
    }
}

__global__ __launch_bounds__(256)
void k_mlp(const half_t* __restrict__ hA, const float* __restrict__ w1,
           const float* __restrict__ b1, const float* __restrict__ w2,
           const float* __restrict__ b2, float* __restrict__ out) {
    int n = blockIdx.x * blockDim.x + threadIdx.x;
    if (n >= N_) return;
    float h[RH_];
    const half8* h8 = (const half8*)(hA + (size_t)n * RH_);
#pragma unroll
    for (int c = 0; c < 8; ++c) {
        half8 v = h8[c];
#pragma unroll
        for (int i = 0; i < 8; ++i) h[c * 8 + i] = (float)v[i];
    }
    float acc = b2[0];
#pragma unroll 1
    for (int j = 0; j < RH_; ++j) {
        float v = b1[j];
#pragma unroll
        for (int k = 0; k < RH_; ++k) v += w1[j * RH_ + k] * h[k];
        v = v > 0.0f ? v : 0.0f;
        acc += w2[j] * v;
    }
    out[n] = acc;
}

extern "C" void kernel_launch(void* const* d_in, const int* in_sizes, int n_in,
                              void* d_out, int out_size, void* d_ws, size_t ws_size,
                              hipStream_t stream) {
    const float* dyn     = (const float*)d_in[0];
    const float* statics = (const float*)d_in[1];
    const int*   ei      = (const int*)d_in[2];
    const float* w0      = (const float*)d_in[3];
    const float* b0      = (const float*)d_in[4];
    const float* w1      = (const float*)d_in[5];
    const float* b1      = (const float*)d_in[6];
    const float* wih     = (const float*)d_in[7];
    const float* whh     = (const float*)d_in[8];
    const float* bih     = (const float*)d_in[9];
    const float* bhh     = (const float*)d_in[10];
    const float* mw1     = (const float*)d_in[11];
    const float* mb1     = (const float*)d_in[12];
    const float* mw2     = (const float*)d_in[13];
    const float* mb2     = (const float*)d_in[14];
    const int* src = ei;
    const int* dst = ei + E_;

    char* ws = (char*)d_ws;
    auto alloc = [&](size_t elems) {        // 4B units, 256B-aligned
        elems = (elems + 63) & ~(size_t)63;
        void* p = ws; ws += elems * 4; return p;
    };
    const int NPAD = N_ + 64;
    int*    deg     = (int*)alloc(N_);
    int*    row_ptr = (int*)alloc(N_ + 4);
    int*    bsum    = (int*)alloc(256);
    int*    cnt     = (int*)alloc((size_t)N_ * 16);
    int*    rp2     = (int*)alloc((size_t)N_ * 16);
    int2*   erec    = (int2*)alloc((size_t)E_ * 2);
    float*  dinv    = (float*)alloc(N_);
    float*  selfn   = (float*)alloc(N_);
    half_t* h0s     = (half_t*)alloc((size_t)N_ * GH_ / 2);        // f16 [N,32]
    float*  csagg   = (float*)alloc(32 * N_);
    half_t* g1blk   = (half_t*)alloc((size_t)N_ * TB_ * GH_ / 2);  // f16 [N][16][32]
    half_t* xblk    = (half_t*)alloc(((size_t)TB_ * N_ + 64) * GH_ / 2); // f16 [16][N][32]
    half_t* hA      = (half_t*)alloc((size_t)NPAD * RH_ / 2);      // f16 [Npad][64]
    half_t* dynT    = (half_t*)alloc((size_t)N_ * 64 / 2);         // f16 [N][64]
    float*  aT      = (float*)alloc(64 * N_);
    half_t* wTh     = (half_t*)alloc(96 * 192 / 2);

    auto cdiv = [](long long x, int b) { return (unsigned)((x + b - 1) / b); };
    const int B = 256;
    const unsigned NB = cdiv(N_, B);       // 196
    const unsigned GB = cdiv(N_, 64);      // 782

    hipMemsetAsync(cnt, 0, (size_t)N_ * 16 * sizeof(int), stream);
    hipMemsetAsync(hA, 0, (size_t)NPAD * RH_ * sizeof(half_t), stream);

    k_transpose<<<cdiv(N_, 64), dim3(64, 4), 0, stream>>>(dyn, dynT);
    k_hist<<<cdiv(E_, B), B, 0, stream>>>(src, dst, cnt);
    k_degsum<<<NB, B, 0, stream>>>(cnt, deg);
    k_scanA<<<NB, B, 0, stream>>>(deg, row_ptr, bsum);
    k_scanB<<<1, B, 0, stream>>>(bsum, (int)NB);
    k_scanC<<<NB, B, 0, stream>>>(row_ptr, bsum);
    k_rowscan<<<NB, B, 0, stream>>>(row_ptr, cnt, rp2);
    k_node_init<<<NB, B, 0, stream>>>(deg, statics, w0, dinv, selfn, h0s);
    k_scatter2<<<cdiv(E_, B), B, 0, stream>>>(src, dst, dinv, rp2, cnt, erec);
    k_wt<<<cdiv(96 * 192, B), B, 0, stream>>>(wih, whh, wTh);
    k_gather16s<<<cdiv((long long)N_ * 4, B), B, 0, stream>>>(row_ptr, erec, selfn,
                                                              h0s, csagg);
    k_aall<<<cdiv((long long)N_ * 64, B), B, 0, stream>>>(row_ptr, erec, selfn,
                                                          dynT, aT);

    k_g1blk<<<NB, B, 0, stream>>>(aT, csagg, w0, b0, w1, g1blk, 0);
    for (int p = 0; p < NP_; ++p) {
        k_gatherx<<<cdiv((long long)N_ * 16, B), B, 0, stream>>>(row_ptr, erec, selfn,
                                                                 g1blk, b1, xblk);
        int do_g1 = (p + 1 < NP_) ? 1 : 0;
        unsigned grid = GB + (do_g1 ? NB : 0);
        k_gru_g1<<<grid, B, 0, stream>>>(xblk, wTh, bih, bhh, hA,
                                         aT, csagg, w0, b0, w1, g1blk,
                                         (p + 1) * TB_, do_g1);
    }
    k_mlp<<<NB, B, 0, stream>>>(hA, mw1, mb1, mw2, mb2, (float*)d_out);
}